// Round 2
// baseline (1350.110 us; speedup 1.0000x reference)
//
#include <hip/hip_runtime.h>
#include <hip/hip_bf16.h>

// MultiStreamAttention: B=8 H=W=64 C=384, heads=8 d=48, r=4 -> Hc=Wc=16 Nc=256, topk=4
// Inputs may be f32 or bf16 (runtime-detected); compute in bf16/f32, output per detected mode.

#define Bq 8
#define Hh 8
#define Dd 48
#define Cc 384
#define NC 256
#define MFINE 32768    // B*H*W
#define KDIM 384
#define SCALE 0.14433756729740643f  // 1/sqrt(48)

typedef __attribute__((ext_vector_type(8))) short short8;
typedef __attribute__((ext_vector_type(4))) float floatx4;

// plane strides (elements)
#define QKVC_PLANE 786432      // B*h*Nc*d
#define QKVW_PLANE 12582912    // B*h*Nc*16*d

// ---- 0a. dtype detector: flag=1 if inputs are f32, 0 if bf16 ----
__global__ __launch_bounds__(256) void k_detect(const ushort* x, int* flag) {
    __shared__ int cnt;
    if (threadIdx.x == 0) cnt = 0;
    __syncthreads();
    int c = 0;
    for (int i = threadIdx.x; i < 8192; i += 256) {
        int e = (x[i] >> 7) & 0xFF;
        if (e >= 0xC1) c++;   // |v| >= 2^66: never for sane bf16 data, ~12% for f32-as-bf16
    }
    atomicAdd(&cnt, c);
    __syncthreads();
    if (threadIdx.x == 0) *flag = (cnt > 16) ? 1 : 0;
}

// ---- 0b. canonicalize input to bf16 ----
__global__ __launch_bounds__(256) void k_convert(const void* src, __hip_bfloat16* dst, int n, const int* flag) {
    int i = blockIdx.x * 256 + threadIdx.x;
    if (i >= n) return;
    if (*flag) dst[i] = __float2bfloat16(((const float*)src)[i]);
    else       dst[i] = ((const __hip_bfloat16*)src)[i];
}

__device__ __forceinline__ floatx4 mfma_tile(const ushort* A, const ushort* W,
                                             int tile_m, int tile_n, int lane) {
    int row16 = lane & 15, quad = lane >> 4;
    const ushort* arow = A + (size_t)(tile_m + row16) * KDIM + quad * 8;
    const ushort* brow = W + (size_t)(tile_n + row16) * KDIM + quad * 8;
    floatx4 acc = {0.f, 0.f, 0.f, 0.f};
    for (int kk = 0; kk < KDIM; kk += 32) {
        short8 af = *(const short8*)(arow + kk);
        short8 bf = *(const short8*)(brow + kk);
        acc = __builtin_amdgcn_mfma_f32_16x16x32_bf16(af, bf, acc, 0, 0, 0);
    }
    return acc;
}

// ---- 1. pool: xbf (B,64,64,C) -> xc bf16 (B*Nc, C) ----
__global__ __launch_bounds__(256) void k_pool(const __hip_bfloat16* x, __hip_bfloat16* xc) {
    int blk = blockIdx.x;            // b*256 + n
    int b = blk >> 8, n = blk & 255;
    int yc = n >> 4, xcc = n & 15;
    for (int c = threadIdx.x; c < Cc; c += blockDim.x) {
        float s = 0.f;
        for (int i = 0; i < 4; i++)
            for (int j = 0; j < 4; j++)
                s += __bfloat162float(x[(((size_t)(b * 64 + yc * 4 + i)) * 64 + xcc * 4 + j) * Cc + c]);
        xc[(size_t)blk * Cc + c] = __float2bfloat16(s * 0.0625f);
    }
}

// ---- 2. coarse qkv gemm: (2048x384)@(1152x384)^T -> q/k/v f32 planes (B,h,Nc,d) ----
__global__ __launch_bounds__(256) void k_gemm_qkv_coarse(const ushort* A, const ushort* W, float* qkvc) {
    int lane = threadIdx.x & 63, wave = threadIdx.x >> 6;
    int tile_m = blockIdx.y * 32 + (wave >> 1) * 16;
    int tile_n = blockIdx.x * 32 + (wave & 1) * 16;
    floatx4 acc = mfma_tile(A, W, tile_m, tile_n, lane);
    int row16 = lane & 15, quad = lane >> 4;
    int n = tile_n + row16;
    int which = n / Cc, hd = n % Cc, head = hd / Dd, dim = hd % Dd;
    for (int rr = 0; rr < 4; rr++) {
        int m = tile_m + quad * 4 + rr;
        int b = m >> 8, nc = m & 255;
        qkvc[(size_t)which * QKVC_PLANE + (((size_t)(b * Hh + head) * NC + nc) * Dd + dim)] = acc[rr];
    }
}

// ---- 3. coarse attention: per (b,h,qi) block ----
__global__ __launch_bounds__(256) void k_coarse_attn(const float* qkvc, int* idx_out, __hip_bfloat16* xo) {
    __shared__ float qs[Dd];
    __shared__ float lg[NC];
    __shared__ float rv[NC];
    __shared__ int ri[NC];
    __shared__ float ps[NC];
    __shared__ int sel[4];
    __shared__ unsigned char chosen[NC];
    int t = threadIdx.x;
    int bh = blockIdx.x >> 8;   // b*8+h
    int qi = blockIdx.x & 255;
    const float* qp = qkvc + ((size_t)bh * NC + qi) * Dd;
    const float* kp = qkvc + QKVC_PLANE + (size_t)bh * NC * Dd;
    const float* vp = qkvc + 2 * QKVC_PLANE + (size_t)bh * NC * Dd;
    if (t < Dd) qs[t] = qp[t];
    chosen[t] = 0;
    __syncthreads();
    {
        const float* kr = kp + (size_t)t * Dd;
        float s = 0.f;
        for (int j = 0; j < Dd; j++) s += qs[j] * kr[j];
        lg[t] = s * SCALE;
    }
    __syncthreads();
    // top-4 (ties -> smallest index, matching lax.top_k)
    for (int it = 0; it < 4; it++) {
        rv[t] = chosen[t] ? -3.402823e38f : lg[t];
        ri[t] = t;
        __syncthreads();
        for (int st = 128; st > 0; st >>= 1) {
            if (t < st) {
                float ov = rv[t + st]; int oi = ri[t + st];
                if (ov > rv[t] || (ov == rv[t] && oi < ri[t])) { rv[t] = ov; ri[t] = oi; }
            }
            __syncthreads();
        }
        if (t == 0) { sel[it] = ri[0]; chosen[ri[0]] = 1; }
        __syncthreads();
    }
    if (t < 4) idx_out[(size_t)blockIdx.x * 4 + t] = sel[t];
    // softmax over all 256
    rv[t] = lg[t];
    __syncthreads();
    for (int st = 128; st > 0; st >>= 1) { if (t < st) rv[t] = fmaxf(rv[t], rv[t + st]); __syncthreads(); }
    float mx = rv[0];
    __syncthreads();
    float e = expf(lg[t] - mx);
    ps[t] = e; rv[t] = e;
    __syncthreads();
    for (int st = 128; st > 0; st >>= 1) { if (t < st) rv[t] += rv[t + st]; __syncthreads(); }
    float inv = 1.0f / rv[0];
    __syncthreads();
    if (t < Dd) {
        float acc = 0.f;
        for (int k = 0; k < NC; k++) acc += ps[k] * vp[(size_t)k * Dd + t];
        acc *= inv;
        int b = bh >> 3, hh = bh & 7;
        xo[((size_t)(b * NC + qi)) * Cc + hh * Dd + t] = __float2bfloat16(acc);
    }
}

// ---- 4. fine qkv gemm: (32768x384)@(1152x384)^T -> window-layout bf16 planes ----
__global__ __launch_bounds__(256) void k_gemm_qkv_fine(const ushort* A, const ushort* W, __hip_bfloat16* qkvw) {
    int lane = threadIdx.x & 63, wave = threadIdx.x >> 6;
    int tile_m = blockIdx.y * 32 + (wave >> 1) * 16;
    int tile_n = blockIdx.x * 32 + (wave & 1) * 16;
    floatx4 acc = mfma_tile(A, W, tile_m, tile_n, lane);
    int row16 = lane & 15, quad = lane >> 4;
    int n = tile_n + row16;
    int which = n / Cc, hd = n % Cc, head = hd / Dd, dim = hd % Dd;
    for (int rr = 0; rr < 4; rr++) {
        int m = tile_m + quad * 4 + rr;
        int b = m >> 12, pix = m & 4095;
        int y = pix >> 6, x = pix & 63;
        int win = (y >> 2) * 16 + (x >> 2);
        int pos = (y & 3) * 4 + (x & 3);
        size_t dst = (size_t)which * QKVW_PLANE + ((((size_t)(b * Hh + head) * NC + win) * 16 + pos) * Dd + dim);
        qkvw[dst] = __float2bfloat16(acc[rr]);
    }
}

// ---- 5. window attention: per (b,h,n) block ----
__global__ __launch_bounds__(256) void k_win_attn(const __hip_bfloat16* qkvw, const int* idx, __hip_bfloat16* yo) {
    __shared__ float Qs[16 * Dd];
    __shared__ float Ks[64 * Dd];
    __shared__ float Vs[64 * Dd];
    __shared__ float S[16 * 64];
    __shared__ int sel[4];
    int t = threadIdx.x;
    int bh = blockIdx.x >> 8, n = blockIdx.x & 255;
    if (t < 4) sel[t] = idx[(size_t)blockIdx.x * 4 + t];
    const __hip_bfloat16* Qp = qkvw + ((size_t)bh * NC + n) * (16 * Dd);
    for (int e = t; e < 16 * Dd; e += 256) Qs[e] = __bfloat162float(Qp[e]);
    __syncthreads();
    for (int g = 0; g < 4; g++) {
        const __hip_bfloat16* Kp = qkvw + QKVW_PLANE + ((size_t)bh * NC + sel[g]) * (16 * Dd);
        const __hip_bfloat16* Vp = qkvw + 2 * QKVW_PLANE + ((size_t)bh * NC + sel[g]) * (16 * Dd);
        for (int e = t; e < 16 * Dd; e += 256) {
            Ks[g * 16 * Dd + e] = __bfloat162float(Kp[e]);
            Vs[g * 16 * Dd + e] = __bfloat162float(Vp[e]);
        }
    }
    __syncthreads();
    for (int e = t; e < 1024; e += 256) {
        int q = e >> 6, k = e & 63;
        float s = 0.f;
        for (int j = 0; j < Dd; j++) s += Qs[q * Dd + j] * Ks[k * Dd + j];
        S[e] = s * SCALE;
    }
    __syncthreads();
    if (t < 16) {
        float mx = -3.402823e38f;
        for (int k = 0; k < 64; k++) mx = fmaxf(mx, S[t * 64 + k]);
        float sum = 0.f;
        for (int k = 0; k < 64; k++) { float e2 = expf(S[t * 64 + k] - mx); S[t * 64 + k] = e2; sum += e2; }
        float inv = 1.f / sum;
        for (int k = 0; k < 64; k++) S[t * 64 + k] *= inv;
    }
    __syncthreads();
    int b = bh >> 3, hh = bh & 7;
    int wy = n >> 4, wx = n & 15;
    for (int e = t; e < 16 * Dd; e += 256) {
        int q = e / Dd, dd = e % Dd;
        float acc = 0.f;
        for (int k = 0; k < 64; k++) acc += S[q * 64 + k] * Vs[k * Dd + dd];
        int y = wy * 4 + (q >> 2), x = wx * 4 + (q & 3);
        yo[(((size_t)(b * 64 + y)) * 64 + x) * Cc + hh * Dd + dd] = __float2bfloat16(acc);
    }
}

// ---- 6. upsample(xo) -> dwconv(dwx) -> 0.5*xn + 0.5*yo -> zpre ----
__global__ __launch_bounds__(256) void k_up_mix(const __hip_bfloat16* xo, const __hip_bfloat16* yo,
                                                const __hip_bfloat16* dwx_w, const __hip_bfloat16* dwx_b,
                                                __hip_bfloat16* zpre) {
    __shared__ float wsm[Cc * 9];
    __shared__ float bsm[Cc];
    for (int e = threadIdx.x; e < Cc * 9; e += 256) wsm[e] = __bfloat162float(dwx_w[e]);
    for (int e = threadIdx.x; e < Cc; e += 256) bsm[e] = __bfloat162float(dwx_b[e]);
    __syncthreads();
    size_t gid = (size_t)blockIdx.x * 256 + threadIdx.x;
    int c = (int)(gid % Cc);
    size_t p = gid / Cc;
    int x = (int)(p % 64); p /= 64;
    int y = (int)(p % 64);
    int b = (int)(p / 64);
    float acc = bsm[c];
    for (int di = 0; di < 3; di++) {
        int yy = y + di - 1;
        if (yy < 0 || yy > 63) continue;
        for (int dj = 0; dj < 3; dj++) {
            int xx = x + dj - 1;
            if (xx < 0 || xx > 63) continue;
            acc += __bfloat162float(xo[((size_t)(b * NC + (yy >> 2) * 16 + (xx >> 2))) * Cc + c]) * wsm[c * 9 + di * 3 + dj];
        }
    }
    float z = 0.5f * acc + 0.5f * __bfloat162float(yo[gid]);
    zpre[gid] = __float2bfloat16(z);
}

// ---- 7. dwconv(dw) on zpre -> z ----
__global__ __launch_bounds__(256) void k_dw2(const __hip_bfloat16* zpre, const __hip_bfloat16* dw_w,
                                             const __hip_bfloat16* dw_b, __hip_bfloat16* z) {
    __shared__ float wsm[Cc * 9];
    __shared__ float bsm[Cc];
    for (int e = threadIdx.x; e < Cc * 9; e += 256) wsm[e] = __bfloat162float(dw_w[e]);
    for (int e = threadIdx.x; e < Cc; e += 256) bsm[e] = __bfloat162float(dw_b[e]);
    __syncthreads();
    size_t gid = (size_t)blockIdx.x * 256 + threadIdx.x;
    int c = (int)(gid % Cc);
    size_t p = gid / Cc;
    int x = (int)(p % 64); p /= 64;
    int y = (int)(p % 64);
    int b = (int)(p / 64);
    float acc = bsm[c];
    for (int di = 0; di < 3; di++) {
        int yy = y + di - 1;
        if (yy < 0 || yy > 63) continue;
        for (int dj = 0; dj < 3; dj++) {
            int xx = x + dj - 1;
            if (xx < 0 || xx > 63) continue;
            acc += __bfloat162float(zpre[(((size_t)(b * 64 + yy)) * 64 + xx) * Cc + c]) * wsm[c * 9 + di * 3 + dj];
        }
    }
    z[gid] = __float2bfloat16(acc);
}

// ---- 8. pointwise gemm + bias -> out (dtype per flag) ----
__global__ __launch_bounds__(256) void k_gemm_pw(const ushort* Z, const ushort* W, const __hip_bfloat16* bias,
                                                 void* out, const int* flag) {
    int lane = threadIdx.x & 63, wave = threadIdx.x >> 6;
    int tile_m = blockIdx.y * 32 + (wave >> 1) * 16;
    int tile_n = blockIdx.x * 32 + (wave & 1) * 16;
    floatx4 acc = mfma_tile(Z, W, tile_m, tile_n, lane);
    int row16 = lane & 15, quad = lane >> 4;
    int n = tile_n + row16;
    float bv = __bfloat162float(bias[n]);
    int f32out = *flag;
    for (int rr = 0; rr < 4; rr++) {
        int m = tile_m + quad * 4 + rr;
        float v = acc[rr] + bv;
        if (f32out) ((float*)out)[(size_t)m * Cc + n] = v;
        else ((__hip_bfloat16*)out)[(size_t)m * Cc + n] = __float2bfloat16(v);
    }
}

extern "C" void kernel_launch(void* const* d_in, const int* in_sizes, int n_in,
                              void* d_out, int out_size, void* d_ws, size_t ws_size,
                              hipStream_t stream) {
    char* ws = (char*)d_ws;
    float*          qkvc = (float*)(ws);                        //  9,437,184 B (3 f32 planes)
    __hip_bfloat16* xc   = (__hip_bfloat16*)(ws +  9437184);    //  1,572,864 B
    int*            idx  = (int*)(ws + 11010048);               //    262,144 B
    __hip_bfloat16* xo   = (__hip_bfloat16*)(ws + 11272192);    //  1,572,864 B
    __hip_bfloat16* qkvw = (__hip_bfloat16*)(ws + 12845056);    // 75,497,472 B (3 bf16 planes)
    __hip_bfloat16* yo   = (__hip_bfloat16*)(ws + 88342528);    // 25,165,824 B
    // xbf aliases yo region (x is dead before win_attn writes yo);
    // zpre aliases qkvw (dead after win_attn); zbuf aliases yo (dead after up_mix)
    __hip_bfloat16* xbf  = (__hip_bfloat16*)(ws + 88342528);
    __hip_bfloat16* zpre = (__hip_bfloat16*)(ws + 12845056);
    __hip_bfloat16* zbuf = (__hip_bfloat16*)(ws + 88342528);
    // converted weights
    __hip_bfloat16* wqkv = (__hip_bfloat16*)(ws + 113508352);   //   884,736 B
    __hip_bfloat16* wdwx = (__hip_bfloat16*)(ws + 114393088);   //     6,912 B
    __hip_bfloat16* bdwx = (__hip_bfloat16*)(ws + 114400000);   //       768 B
    __hip_bfloat16* wdw  = (__hip_bfloat16*)(ws + 114400768);   //     6,912 B
    __hip_bfloat16* bdw  = (__hip_bfloat16*)(ws + 114407680);   //       768 B
    __hip_bfloat16* wpw  = (__hip_bfloat16*)(ws + 114408448);   //   294,912 B
    __hip_bfloat16* bpw  = (__hip_bfloat16*)(ws + 114703360);   //       768 B
    int*            flag = (int*)(ws + 114704128);

    k_detect<<<1, 256, 0, stream>>>((const ushort*)d_in[0], flag);
    k_convert<<<49152, 256, 0, stream>>>(d_in[0], xbf, 12582912, flag);
    k_convert<<<1728, 256, 0, stream>>>(d_in[1], wqkv, 442368, flag);
    k_convert<<<14, 256, 0, stream>>>(d_in[2], wdwx, 3456, flag);
    k_convert<<<2, 256, 0, stream>>>(d_in[3], bdwx, 384, flag);
    k_convert<<<14, 256, 0, stream>>>(d_in[4], wdw, 3456, flag);
    k_convert<<<2, 256, 0, stream>>>(d_in[5], bdw, 384, flag);
    k_convert<<<576, 256, 0, stream>>>(d_in[6], wpw, 147456, flag);
    k_convert<<<2, 256, 0, stream>>>(d_in[7], bpw, 384, flag);

    k_pool<<<2048, 256, 0, stream>>>(xbf, xc);
    k_gemm_qkv_coarse<<<dim3(36, 64), 256, 0, stream>>>((const ushort*)xc, (const ushort*)wqkv, qkvc);
    k_coarse_attn<<<16384, 256, 0, stream>>>(qkvc, idx, xo);
    k_gemm_qkv_fine<<<dim3(36, 1024), 256, 0, stream>>>((const ushort*)xbf, (const ushort*)wqkv, qkvw);
    k_win_attn<<<16384, 256, 0, stream>>>(qkvw, idx, yo);
    k_up_mix<<<49152, 256, 0, stream>>>(xo, yo, wdwx, bdwx, zpre);
    k_dw2<<<49152, 256, 0, stream>>>(zpre, wdw, bdw, zbuf);
    k_gemm_pw<<<dim3(12, 1024), 256, 0, stream>>>((const ushort*)zbuf, (const ushort*)wpw, bpw, d_out, flag);
}

// Round 3
// 928.316 us; speedup vs baseline: 1.4544x; 1.4544x over previous
//
#include <hip/hip_runtime.h>
#include <hip/hip_bf16.h>

// MultiStreamAttention: B=8 H=W=64 C=384, heads=8 d=48, r=4 -> Hc=Wc=16 Nc=256, topk=4
// Inputs f32 or bf16 (runtime-detected); compute bf16 MFMA / f32 accum; output per detected mode.

#define Bq 8
#define Hh 8
#define Dd 48
#define Cc 384
#define NC 256
#define MFINE 32768    // B*H*W
#define KDIM 384
#define SCALE 0.14433756729740643f  // 1/sqrt(48)

typedef __attribute__((ext_vector_type(8))) short short8;
typedef __attribute__((ext_vector_type(4))) float floatx4;

// plane strides (elements)
#define QKVC_PLANE 786432      // B*h*Nc*d
#define QKVW_PLANE 12582912    // B*h*Nc*16*d

// ---- 0a. dtype detector: flag=1 if inputs are f32, 0 if bf16 ----
__global__ __launch_bounds__(256) void k_detect(const ushort* x, int* flag) {
    __shared__ int cnt;
    if (threadIdx.x == 0) cnt = 0;
    __syncthreads();
    int c = 0;
    for (int i = threadIdx.x; i < 8192; i += 256) {
        int e = (x[i] >> 7) & 0xFF;
        if (e >= 0xC1) c++;   // |v| >= 2^66: never for sane bf16 data, ~12% for f32-as-bf16
    }
    atomicAdd(&cnt, c);
    __syncthreads();
    if (threadIdx.x == 0) *flag = (cnt > 16) ? 1 : 0;
}

// ---- 0b. canonicalize input to bf16 ----
__global__ __launch_bounds__(256) void k_convert(const void* src, __hip_bfloat16* dst, int n, const int* flag) {
    int i = blockIdx.x * 256 + threadIdx.x;
    if (i >= n) return;
    if (*flag) dst[i] = __float2bfloat16(((const float*)src)[i]);
    else       dst[i] = ((const __hip_bfloat16*)src)[i];
}

// ---- async global->LDS, 16B per lane, wave-uniform LDS base ----
__device__ __forceinline__ void gload_lds16(const ushort* g, short* l) {
    __builtin_amdgcn_global_load_lds(
        (const __attribute__((address_space(1))) unsigned int*)(g),
        (__attribute__((address_space(3))) unsigned int*)(l), 16, 0, 0);
}

// ---- m97-style 128x128 tiled GEMM core: C[128x128] = A[128xK] * B[128xK]^T ----
// 4 waves, each computes a 64x64 quadrant via 4x4 16x16x32 MFMA accumulators.
__device__ __forceinline__ void gemm128(const ushort* A, const ushort* B,
                                        int tile_m, int tile_n,
                                        short* As, short* Bs, floatx4 (&acc)[4][4]) {
    int lane = threadIdx.x & 63, wave = threadIdx.x >> 6;
    int m_off = (wave >> 1) * 64, n_off = (wave & 1) * 64;
    int row16 = lane & 15, quad = lane >> 4;
    int srow = lane >> 2;          // 0..15 within a 16-row staging group
    int scol = (lane & 3) * 8;     // element offset within 32-col K-tile
    for (int i = 0; i < 4; i++)
        for (int j = 0; j < 4; j++)
            acc[i][j] = (floatx4){0.f, 0.f, 0.f, 0.f};
    for (int k0 = 0; k0 < KDIM; k0 += 32) {
        // stage 128x32 A and B tiles: 8 groups of 16 rows each, 2 groups per wave per matrix
        for (int g = wave; g < 8; g += 4) {
            int r = g * 16 + srow;
            gload_lds16(A + (size_t)(tile_m + r) * KDIM + k0 + scol, As + g * 512);
            gload_lds16(B + (size_t)(tile_n + r) * KDIM + k0 + scol, Bs + g * 512);
        }
        __syncthreads();   // drains vmcnt (global_load_lds) per compiler barrier semantics
        short8 af[4], bf[4];
        for (int mt = 0; mt < 4; mt++)
            af[mt] = *(const short8*)(As + (m_off + mt * 16 + row16) * 32 + quad * 8);
        for (int nt = 0; nt < 4; nt++)
            bf[nt] = *(const short8*)(Bs + (n_off + nt * 16 + row16) * 32 + quad * 8);
        for (int mt = 0; mt < 4; mt++)
            for (int nt = 0; nt < 4; nt++)
                acc[mt][nt] = __builtin_amdgcn_mfma_f32_16x16x32_bf16(af[mt], bf[nt], acc[mt][nt], 0, 0, 0);
        __syncthreads();
    }
}

// naive per-wave 16x16 tile (kept for the small coarse GEMM)
__device__ __forceinline__ floatx4 mfma_tile(const ushort* A, const ushort* W,
                                             int tile_m, int tile_n, int lane) {
    int row16 = lane & 15, quad = lane >> 4;
    const ushort* arow = A + (size_t)(tile_m + row16) * KDIM + quad * 8;
    const ushort* brow = W + (size_t)(tile_n + row16) * KDIM + quad * 8;
    floatx4 acc = {0.f, 0.f, 0.f, 0.f};
    for (int kk = 0; kk < KDIM; kk += 32) {
        short8 af = *(const short8*)(arow + kk);
        short8 bf = *(const short8*)(brow + kk);
        acc = __builtin_amdgcn_mfma_f32_16x16x32_bf16(af, bf, acc, 0, 0, 0);
    }
    return acc;
}

// ---- 1. pool: xbf (B,64,64,C) -> xc bf16 (B*Nc, C) ----
__global__ __launch_bounds__(256) void k_pool(const __hip_bfloat16* x, __hip_bfloat16* xc) {
    int blk = blockIdx.x;            // b*256 + n
    int b = blk >> 8, n = blk & 255;
    int yc = n >> 4, xcc = n & 15;
    for (int c = threadIdx.x; c < Cc; c += blockDim.x) {
        float s = 0.f;
        for (int i = 0; i < 4; i++)
            for (int j = 0; j < 4; j++)
                s += __bfloat162float(x[(((size_t)(b * 64 + yc * 4 + i)) * 64 + xcc * 4 + j) * Cc + c]);
        xc[(size_t)blk * Cc + c] = __float2bfloat16(s * 0.0625f);
    }
}

// ---- 2. coarse qkv gemm: (2048x384)@(1152x384)^T -> q/k/v f32 planes (B,h,Nc,d) ----
__global__ __launch_bounds__(256) void k_gemm_qkv_coarse(const ushort* A, const ushort* W, float* qkvc) {
    int lane = threadIdx.x & 63, wave = threadIdx.x >> 6;
    int tile_m = blockIdx.y * 32 + (wave >> 1) * 16;
    int tile_n = blockIdx.x * 32 + (wave & 1) * 16;
    floatx4 acc = mfma_tile(A, W, tile_m, tile_n, lane);
    int row16 = lane & 15, quad = lane >> 4;
    int n = tile_n + row16;
    int which = n / Cc, hd = n % Cc, head = hd / Dd, dim = hd % Dd;
    for (int rr = 0; rr < 4; rr++) {
        int m = tile_m + quad * 4 + rr;
        int b = m >> 8, nc = m & 255;
        qkvc[(size_t)which * QKVC_PLANE + (((size_t)(b * Hh + head) * NC + nc) * Dd + dim)] = acc[rr];
    }
}

// ---- 3. coarse attention: per (b,h,qi) block ----
__global__ __launch_bounds__(256) void k_coarse_attn(const float* qkvc, int* idx_out, __hip_bfloat16* xo) {
    __shared__ float qs[Dd];
    __shared__ float lg[NC];
    __shared__ float rv[NC];
    __shared__ int ri[NC];
    __shared__ float ps[NC];
    __shared__ int sel[4];
    __shared__ unsigned char chosen[NC];
    int t = threadIdx.x;
    int bh = blockIdx.x >> 8;   // b*8+h
    int qi = blockIdx.x & 255;
    const float* qp = qkvc + ((size_t)bh * NC + qi) * Dd;
    const float* kp = qkvc + QKVC_PLANE + (size_t)bh * NC * Dd;
    const float* vp = qkvc + 2 * QKVC_PLANE + (size_t)bh * NC * Dd;
    if (t < Dd) qs[t] = qp[t];
    chosen[t] = 0;
    __syncthreads();
    {
        const float* kr = kp + (size_t)t * Dd;
        float s = 0.f;
        for (int j = 0; j < Dd; j++) s += qs[j] * kr[j];
        lg[t] = s * SCALE;
    }
    __syncthreads();
    // top-4 (ties -> smallest index, matching lax.top_k)
    for (int it = 0; it < 4; it++) {
        rv[t] = chosen[t] ? -3.402823e38f : lg[t];
        ri[t] = t;
        __syncthreads();
        for (int st = 128; st > 0; st >>= 1) {
            if (t < st) {
                float ov = rv[t + st]; int oi = ri[t + st];
                if (ov > rv[t] || (ov == rv[t] && oi < ri[t])) { rv[t] = ov; ri[t] = oi; }
            }
            __syncthreads();
        }
        if (t == 0) { sel[it] = ri[0]; chosen[ri[0]] = 1; }
        __syncthreads();
    }
    if (t < 4) idx_out[(size_t)blockIdx.x * 4 + t] = sel[t];
    // softmax over all 256
    rv[t] = lg[t];
    __syncthreads();
    for (int st = 128; st > 0; st >>= 1) { if (t < st) rv[t] = fmaxf(rv[t], rv[t + st]); __syncthreads(); }
    float mx = rv[0];
    __syncthreads();
    float e = expf(lg[t] - mx);
    ps[t] = e; rv[t] = e;
    __syncthreads();
    for (int st = 128; st > 0; st >>= 1) { if (t < st) rv[t] += rv[t + st]; __syncthreads(); }
    float inv = 1.0f / rv[0];
    __syncthreads();
    if (t < Dd) {
        float acc = 0.f;
        for (int k = 0; k < NC; k++) acc += ps[k] * vp[(size_t)k * Dd + t];
        acc *= inv;
        int b = bh >> 3, hh = bh & 7;
        xo[((size_t)(b * NC + qi)) * Cc + hh * Dd + t] = __float2bfloat16(acc);
    }
}

// ---- 4. fine qkv gemm (tiled): (32768x384)@(1152x384)^T -> window-layout bf16 planes ----
__global__ __launch_bounds__(256) void k_gemm_qkv_fine(const ushort* A, const ushort* W, __hip_bfloat16* qkvw) {
    __shared__ __align__(16) short As[128 * 32];
    __shared__ __align__(16) short Bs[128 * 32];
    floatx4 acc[4][4];
    int tile_m = blockIdx.y * 128, tile_n = blockIdx.x * 128;
    gemm128(A, W, tile_m, tile_n, As, Bs, acc);
    int lane = threadIdx.x & 63, wave = threadIdx.x >> 6;
    int m_off = (wave >> 1) * 64, n_off = (wave & 1) * 64;
    int row16 = lane & 15, quad = lane >> 4;
    for (int nt = 0; nt < 4; nt++) {
        int n = tile_n + n_off + nt * 16 + row16;
        int which = n / Cc, hd = n % Cc, head = hd / Dd, dim = hd % Dd;
        size_t basep = (size_t)which * QKVW_PLANE + (size_t)head * (NC * 16 * Dd) + dim;
        for (int mt = 0; mt < 4; mt++) {
            for (int rr = 0; rr < 4; rr++) {
                int m = tile_m + m_off + mt * 16 + quad * 4 + rr;
                int b = m >> 12, pix = m & 4095;
                int y = pix >> 6, x = pix & 63;
                int win = (y >> 2) * 16 + (x >> 2);
                int pos = (y & 3) * 4 + (x & 3);
                size_t dst = basep + ((size_t)b * Hh * NC * 16 * Dd) + ((size_t)win * 16 + pos) * Dd;
                qkvw[dst] = __float2bfloat16(acc[mt][nt][rr]);
            }
        }
    }
}

// ---- 5. window attention: per (b,h,n) block ----
__global__ __launch_bounds__(256) void k_win_attn(const __hip_bfloat16* qkvw, const int* idx, __hip_bfloat16* yo) {
    __shared__ float Qs[16 * Dd];
    __shared__ float Ks[64 * Dd];
    __shared__ float Vs[64 * Dd];
    __shared__ float S[16 * 64];
    __shared__ int sel[4];
    int t = threadIdx.x;
    int bh = blockIdx.x >> 8, n = blockIdx.x & 255;
    if (t < 4) sel[t] = idx[(size_t)blockIdx.x * 4 + t];
    const __hip_bfloat16* Qp = qkvw + ((size_t)bh * NC + n) * (16 * Dd);
    for (int e = t; e < 16 * Dd; e += 256) Qs[e] = __bfloat162float(Qp[e]);
    __syncthreads();
    for (int g = 0; g < 4; g++) {
        const __hip_bfloat16* Kp = qkvw + QKVW_PLANE + ((size_t)bh * NC + sel[g]) * (16 * Dd);
        const __hip_bfloat16* Vp = qkvw + 2 * QKVW_PLANE + ((size_t)bh * NC + sel[g]) * (16 * Dd);
        for (int e = t; e < 16 * Dd; e += 256) {
            Ks[g * 16 * Dd + e] = __bfloat162float(Kp[e]);
            Vs[g * 16 * Dd + e] = __bfloat162float(Vp[e]);
        }
    }
    __syncthreads();
    for (int e = t; e < 1024; e += 256) {
        int q = e >> 6, k = e & 63;
        float s = 0.f;
        for (int j = 0; j < Dd; j++) s += Qs[q * Dd + j] * Ks[k * Dd + j];
        S[e] = s * SCALE;
    }
    __syncthreads();
    if (t < 16) {
        float mx = -3.402823e38f;
        for (int k = 0; k < 64; k++) mx = fmaxf(mx, S[t * 64 + k]);
        float sum = 0.f;
        for (int k = 0; k < 64; k++) { float e2 = expf(S[t * 64 + k] - mx); S[t * 64 + k] = e2; sum += e2; }
        float inv = 1.f / sum;
        for (int k = 0; k < 64; k++) S[t * 64 + k] *= inv;
    }
    __syncthreads();
    int b = bh >> 3, hh = bh & 7;
    int wy = n >> 4, wx = n & 15;
    for (int e = t; e < 16 * Dd; e += 256) {
        int q = e / Dd, dd = e % Dd;
        float acc = 0.f;
        for (int k = 0; k < 64; k++) acc += S[q * 64 + k] * Vs[k * Dd + dd];
        int y = wy * 4 + (q >> 2), x = wx * 4 + (q & 3);
        yo[(((size_t)(b * 64 + y)) * 64 + x) * Cc + hh * Dd + dd] = __float2bfloat16(acc);
    }
}

// ---- 6. upsample(xo) -> dwconv(dwx) -> 0.5*xn + 0.5*yo -> zpre ----
__global__ __launch_bounds__(256) void k_up_mix(const __hip_bfloat16* xo, const __hip_bfloat16* yo,
                                                const __hip_bfloat16* dwx_w, const __hip_bfloat16* dwx_b,
                                                __hip_bfloat16* zpre) {
    __shared__ float wsm[Cc * 9];
    __shared__ float bsm[Cc];
    for (int e = threadIdx.x; e < Cc * 9; e += 256) wsm[e] = __bfloat162float(dwx_w[e]);
    for (int e = threadIdx.x; e < Cc; e += 256) bsm[e] = __bfloat162float(dwx_b[e]);
    __syncthreads();
    size_t gid = (size_t)blockIdx.x * 256 + threadIdx.x;
    int c = (int)(gid % Cc);
    size_t p = gid / Cc;
    int x = (int)(p % 64); p /= 64;
    int y = (int)(p % 64);
    int b = (int)(p / 64);
    float acc = bsm[c];
    for (int di = 0; di < 3; di++) {
        int yy = y + di - 1;
        if (yy < 0 || yy > 63) continue;
        for (int dj = 0; dj < 3; dj++) {
            int xx = x + dj - 1;
            if (xx < 0 || xx > 63) continue;
            acc += __bfloat162float(xo[((size_t)(b * NC + (yy >> 2) * 16 + (xx >> 2))) * Cc + c]) * wsm[c * 9 + di * 3 + dj];
        }
    }
    float z = 0.5f * acc + 0.5f * __bfloat162float(yo[gid]);
    zpre[gid] = __float2bfloat16(z);
}

// ---- 7. dwconv(dw) on zpre -> z ----
__global__ __launch_bounds__(256) void k_dw2(const __hip_bfloat16* zpre, const __hip_bfloat16* dw_w,
                                             const __hip_bfloat16* dw_b, __hip_bfloat16* z) {
    __shared__ float wsm[Cc * 9];
    __shared__ float bsm[Cc];
    for (int e = threadIdx.x; e < Cc * 9; e += 256) wsm[e] = __bfloat162float(dw_w[e]);
    for (int e = threadIdx.x; e < Cc; e += 256) bsm[e] = __bfloat162float(dw_b[e]);
    __syncthreads();
    size_t gid = (size_t)blockIdx.x * 256 + threadIdx.x;
    int c = (int)(gid % Cc);
    size_t p = gid / Cc;
    int x = (int)(p % 64); p /= 64;
    int y = (int)(p % 64);
    int b = (int)(p / 64);
    float acc = bsm[c];
    for (int di = 0; di < 3; di++) {
        int yy = y + di - 1;
        if (yy < 0 || yy > 63) continue;
        for (int dj = 0; dj < 3; dj++) {
            int xx = x + dj - 1;
            if (xx < 0 || xx > 63) continue;
            acc += __bfloat162float(zpre[(((size_t)(b * 64 + yy)) * 64 + xx) * Cc + c]) * wsm[c * 9 + di * 3 + dj];
        }
    }
    z[gid] = __float2bfloat16(acc);
}

// ---- 8. pointwise gemm (tiled): (32768x384)@(384x384)^T + bias -> out (dtype per flag) ----
__global__ __launch_bounds__(256) void k_gemm_pw(const ushort* Z, const ushort* W, const __hip_bfloat16* bias,
                                                 void* out, const int* flag) {
    __shared__ __align__(16) short As[128 * 32];
    __shared__ __align__(16) short Bs[128 * 32];
    floatx4 acc[4][4];
    int tile_m = blockIdx.y * 128, tile_n = blockIdx.x * 128;
    gemm128(Z, W, tile_m, tile_n, As, Bs, acc);
    int lane = threadIdx.x & 63, wave = threadIdx.x >> 6;
    int m_off = (wave >> 1) * 64, n_off = (wave & 1) * 64;
    int row16 = lane & 15, quad = lane >> 4;
    int f32out = *flag;
    for (int nt = 0; nt < 4; nt++) {
        int n = tile_n + n_off + nt * 16 + row16;
        float bv = __bfloat162float(bias[n]);
        for (int mt = 0; mt < 4; mt++) {
            for (int rr = 0; rr < 4; rr++) {
                int m = tile_m + m_off + mt * 16 + quad * 4 + rr;
                float v = acc[mt][nt][rr] + bv;
                if (f32out) ((float*)out)[(size_t)m * Cc + n] = v;
                else ((__hip_bfloat16*)out)[(size_t)m * Cc + n] = __float2bfloat16(v);
            }
        }
    }
}

extern "C" void kernel_launch(void* const* d_in, const int* in_sizes, int n_in,
                              void* d_out, int out_size, void* d_ws, size_t ws_size,
                              hipStream_t stream) {
    char* ws = (char*)d_ws;
    float*          qkvc = (float*)(ws);                        //  9,437,184 B (3 f32 planes)
    __hip_bfloat16* xc   = (__hip_bfloat16*)(ws +  9437184);    //  1,572,864 B
    int*            idx  = (int*)(ws + 11010048);               //    262,144 B
    __hip_bfloat16* xo   = (__hip_bfloat16*)(ws + 11272192);    //  1,572,864 B
    __hip_bfloat16* qkvw = (__hip_bfloat16*)(ws + 12845056);    // 75,497,472 B (3 bf16 planes)
    __hip_bfloat16* yo   = (__hip_bfloat16*)(ws + 88342528);    // 25,165,824 B
    // xbf aliases yo region (x is dead before win_attn writes yo);
    // zpre aliases qkvw (dead after win_attn); zbuf aliases yo (dead after up_mix)
    __hip_bfloat16* xbf  = (__hip_bfloat16*)(ws + 88342528);
    __hip_bfloat16* zpre = (__hip_bfloat16*)(ws + 12845056);
    __hip_bfloat16* zbuf = (__hip_bfloat16*)(ws + 88342528);
    // converted weights
    __hip_bfloat16* wqkv = (__hip_bfloat16*)(ws + 113508352);   //   884,736 B
    __hip_bfloat16* wdwx = (__hip_bfloat16*)(ws + 114393088);   //     6,912 B
    __hip_bfloat16* bdwx = (__hip_bfloat16*)(ws + 114400000);   //       768 B
    __hip_bfloat16* wdw  = (__hip_bfloat16*)(ws + 114400768);   //     6,912 B
    __hip_bfloat16* bdw  = (__hip_bfloat16*)(ws + 114407680);   //       768 B
    __hip_bfloat16* wpw  = (__hip_bfloat16*)(ws + 114408448);   //   294,912 B
    __hip_bfloat16* bpw  = (__hip_bfloat16*)(ws + 114703360);   //       768 B
    int*            flag = (int*)(ws + 114704128);

    k_detect<<<1, 256, 0, stream>>>((const ushort*)d_in[0], flag);
    k_convert<<<49152, 256, 0, stream>>>(d_in[0], xbf, 12582912, flag);
    k_convert<<<1728, 256, 0, stream>>>(d_in[1], wqkv, 442368, flag);
    k_convert<<<14, 256, 0, stream>>>(d_in[2], wdwx, 3456, flag);
    k_convert<<<2, 256, 0, stream>>>(d_in[3], bdwx, 384, flag);
    k_convert<<<14, 256, 0, stream>>>(d_in[4], wdw, 3456, flag);
    k_convert<<<2, 256, 0, stream>>>(d_in[5], bdw, 384, flag);
    k_convert<<<576, 256, 0, stream>>>(d_in[6], wpw, 147456, flag);
    k_convert<<<2, 256, 0, stream>>>(d_in[7], bpw, 384, flag);

    k_pool<<<2048, 256, 0, stream>>>(xbf, xc);
    k_gemm_qkv_coarse<<<dim3(36, 64), 256, 0, stream>>>((const ushort*)xc, (const ushort*)wqkv, qkvc);
    k_coarse_attn<<<16384, 256, 0, stream>>>(qkvc, idx, xo);
    k_gemm_qkv_fine<<<dim3(9, 256), 256, 0, stream>>>((const ushort*)xbf, (const ushort*)wqkv, qkvw);
    k_win_attn<<<16384, 256, 0, stream>>>(qkvw, idx, yo);
    k_up_mix<<<49152, 256, 0, stream>>>(xo, yo, wdwx, bdwx, zpre);
    k_dw2<<<49152, 256, 0, stream>>>(zpre, wdw, bdw, zbuf);
    k_gemm_pw<<<dim3(3, 256), 256, 0, stream>>>((const ushort*)zbuf, (const ushort*)wpw, bpw, d_out, flag);
}

// Round 4
// 670.813 us; speedup vs baseline: 2.0126x; 1.3839x over previous
//
#include <hip/hip_runtime.h>
#include <hip/hip_bf16.h>

// MultiStreamAttention: B=8 H=W=64 C=384, heads=8 d=48, r=4 -> Hc=Wc=16 Nc=256, topk=4
// Inputs f32 or bf16 (runtime-detected); compute bf16 MFMA / f32 accum; output per detected mode.

#define Bq 8
#define Hh 8
#define Dd 48
#define Cc 384
#define NC 256
#define MFINE 32768    // B*H*W
#define KDIM 384
#define SCALE 0.14433756729740643f  // 1/sqrt(48)

typedef __attribute__((ext_vector_type(8))) short short8;
typedef __attribute__((ext_vector_type(4))) float floatx4;

// plane strides (elements)
#define QKVC_PLANE 786432      // B*h*Nc*d
#define QKVW_PLANE 12582912    // B*h*Nc*16*d

// ---- 0a. dtype detector: flag=1 if inputs are f32, 0 if bf16 ----
__global__ __launch_bounds__(256) void k_detect(const ushort* x, int* flag) {
    __shared__ int cnt;
    if (threadIdx.x == 0) cnt = 0;
    __syncthreads();
    int c = 0;
    for (int i = threadIdx.x; i < 8192; i += 256) {
        int e = (x[i] >> 7) & 0xFF;
        if (e >= 0xC1) c++;   // |v| >= 2^66: never for sane bf16 data, ~12% for f32-as-bf16
    }
    atomicAdd(&cnt, c);
    __syncthreads();
    if (threadIdx.x == 0) *flag = (cnt > 16) ? 1 : 0;
}

// ---- 0b. canonicalize input to bf16 ----
__global__ __launch_bounds__(256) void k_convert(const void* src, __hip_bfloat16* dst, int n, const int* flag) {
    int i = blockIdx.x * 256 + threadIdx.x;
    if (i >= n) return;
    if (*flag) dst[i] = __float2bfloat16(((const float*)src)[i]);
    else       dst[i] = ((const __hip_bfloat16*)src)[i];
}

// ---- async global->LDS, 16B per lane, wave-uniform LDS base ----
__device__ __forceinline__ void gload_lds16(const ushort* g, short* l) {
    __builtin_amdgcn_global_load_lds(
        (const __attribute__((address_space(1))) unsigned int*)(g),
        (__attribute__((address_space(3))) unsigned int*)(l), 16, 0, 0);
}

// ---- m97-style 128x128 tiled GEMM core: C[128x128] = A[128xK] * B[128xK]^T ----
__device__ __forceinline__ void gemm128(const ushort* A, const ushort* B,
                                        int tile_m, int tile_n,
                                        short* As, short* Bs, floatx4 (&acc)[4][4]) {
    int lane = threadIdx.x & 63, wave = threadIdx.x >> 6;
    int m_off = (wave >> 1) * 64, n_off = (wave & 1) * 64;
    int row16 = lane & 15, quad = lane >> 4;
    int srow = lane >> 2;
    int scol = (lane & 3) * 8;
    for (int i = 0; i < 4; i++)
        for (int j = 0; j < 4; j++)
            acc[i][j] = (floatx4){0.f, 0.f, 0.f, 0.f};
    for (int k0 = 0; k0 < KDIM; k0 += 32) {
        for (int g = wave; g < 8; g += 4) {
            int r = g * 16 + srow;
            gload_lds16(A + (size_t)(tile_m + r) * KDIM + k0 + scol, As + g * 512);
            gload_lds16(B + (size_t)(tile_n + r) * KDIM + k0 + scol, Bs + g * 512);
        }
        __syncthreads();
        short8 af[4], bf[4];
        for (int mt = 0; mt < 4; mt++)
            af[mt] = *(const short8*)(As + (m_off + mt * 16 + row16) * 32 + quad * 8);
        for (int nt = 0; nt < 4; nt++)
            bf[nt] = *(const short8*)(Bs + (n_off + nt * 16 + row16) * 32 + quad * 8);
        for (int mt = 0; mt < 4; mt++)
            for (int nt = 0; nt < 4; nt++)
                acc[mt][nt] = __builtin_amdgcn_mfma_f32_16x16x32_bf16(af[mt], bf[nt], acc[mt][nt], 0, 0, 0);
        __syncthreads();
    }
}

// naive per-wave 16x16 tile (small coarse GEMM)
__device__ __forceinline__ floatx4 mfma_tile(const ushort* A, const ushort* W,
                                             int tile_m, int tile_n, int lane) {
    int row16 = lane & 15, quad = lane >> 4;
    const ushort* arow = A + (size_t)(tile_m + row16) * KDIM + quad * 8;
    const ushort* brow = W + (size_t)(tile_n + row16) * KDIM + quad * 8;
    floatx4 acc = {0.f, 0.f, 0.f, 0.f};
    for (int kk = 0; kk < KDIM; kk += 32) {
        short8 af = *(const short8*)(arow + kk);
        short8 bf = *(const short8*)(brow + kk);
        acc = __builtin_amdgcn_mfma_f32_16x16x32_bf16(af, bf, acc, 0, 0, 0);
    }
    return acc;
}

// ---- 1. pool: xbf (B,64,64,C) -> xc bf16 (B*Nc, C) ----
__global__ __launch_bounds__(256) void k_pool(const __hip_bfloat16* x, __hip_bfloat16* xc) {
    int blk = blockIdx.x;            // b*256 + n
    int b = blk >> 8, n = blk & 255;
    int yc = n >> 4, xcc = n & 15;
    for (int c = threadIdx.x; c < Cc; c += blockDim.x) {
        float s = 0.f;
        for (int i = 0; i < 4; i++)
            for (int j = 0; j < 4; j++)
                s += __bfloat162float(x[(((size_t)(b * 64 + yc * 4 + i)) * 64 + xcc * 4 + j) * Cc + c]);
        xc[(size_t)blk * Cc + c] = __float2bfloat16(s * 0.0625f);
    }
}

// ---- 2. coarse qkv gemm: (2048x384)@(1152x384)^T -> q/k/v f32 planes (B,h,Nc,d) ----
__global__ __launch_bounds__(256) void k_gemm_qkv_coarse(const ushort* A, const ushort* W, float* qkvc) {
    int lane = threadIdx.x & 63, wave = threadIdx.x >> 6;
    int tile_m = blockIdx.y * 32 + (wave >> 1) * 16;
    int tile_n = blockIdx.x * 32 + (wave & 1) * 16;
    floatx4 acc = mfma_tile(A, W, tile_m, tile_n, lane);
    int row16 = lane & 15, quad = lane >> 4;
    int n = tile_n + row16;
    int which = n / Cc, hd = n % Cc, head = hd / Dd, dim = hd % Dd;
    for (int rr = 0; rr < 4; rr++) {
        int m = tile_m + quad * 4 + rr;
        int b = m >> 8, nc = m & 255;
        qkvc[(size_t)which * QKVC_PLANE + (((size_t)(b * Hh + head) * NC + nc) * Dd + dim)] = acc[rr];
    }
}

// ---- 3. coarse attention: per (b,h,qi) block ----
__global__ __launch_bounds__(256) void k_coarse_attn(const float* qkvc, int* idx_out, __hip_bfloat16* xo) {
    __shared__ float qs[Dd];
    __shared__ float lg[NC];
    __shared__ float rv[NC];
    __shared__ int ri[NC];
    __shared__ float ps[NC];
    __shared__ int sel[4];
    __shared__ unsigned char chosen[NC];
    int t = threadIdx.x;
    int bh = blockIdx.x >> 8;   // b*8+h
    int qi = blockIdx.x & 255;
    const float* qp = qkvc + ((size_t)bh * NC + qi) * Dd;
    const float* kp = qkvc + QKVC_PLANE + (size_t)bh * NC * Dd;
    const float* vp = qkvc + 2 * QKVC_PLANE + (size_t)bh * NC * Dd;
    if (t < Dd) qs[t] = qp[t];
    chosen[t] = 0;
    __syncthreads();
    {
        const float* kr = kp + (size_t)t * Dd;
        float s = 0.f;
        for (int j = 0; j < Dd; j++) s += qs[j] * kr[j];
        lg[t] = s * SCALE;
    }
    __syncthreads();
    for (int it = 0; it < 4; it++) {
        rv[t] = chosen[t] ? -3.402823e38f : lg[t];
        ri[t] = t;
        __syncthreads();
        for (int st = 128; st > 0; st >>= 1) {
            if (t < st) {
                float ov = rv[t + st]; int oi = ri[t + st];
                if (ov > rv[t] || (ov == rv[t] && oi < ri[t])) { rv[t] = ov; ri[t] = oi; }
            }
            __syncthreads();
        }
        if (t == 0) { sel[it] = ri[0]; chosen[ri[0]] = 1; }
        __syncthreads();
    }
    if (t < 4) idx_out[(size_t)blockIdx.x * 4 + t] = sel[t];
    rv[t] = lg[t];
    __syncthreads();
    for (int st = 128; st > 0; st >>= 1) { if (t < st) rv[t] = fmaxf(rv[t], rv[t + st]); __syncthreads(); }
    float mx = rv[0];
    __syncthreads();
    float e = expf(lg[t] - mx);
    ps[t] = e; rv[t] = e;
    __syncthreads();
    for (int st = 128; st > 0; st >>= 1) { if (t < st) rv[t] += rv[t + st]; __syncthreads(); }
    float inv = 1.0f / rv[0];
    __syncthreads();
    if (t < Dd) {
        float acc = 0.f;
        for (int k = 0; k < NC; k++) acc += ps[k] * vp[(size_t)k * Dd + t];
        acc *= inv;
        int b = bh >> 3, hh = bh & 7;
        xo[((size_t)(b * NC + qi)) * Cc + hh * Dd + t] = __float2bfloat16(acc);
    }
}

// ---- 4. fine qkv gemm (tiled): (32768x384)@(1152x384)^T -> window-layout bf16 planes ----
__global__ __launch_bounds__(256) void k_gemm_qkv_fine(const ushort* A, const ushort* W, __hip_bfloat16* qkvw) {
    __shared__ __align__(16) short As[128 * 32];
    __shared__ __align__(16) short Bs[128 * 32];
    floatx4 acc[4][4];
    int tile_m = blockIdx.y * 128, tile_n = blockIdx.x * 128;
    gemm128(A, W, tile_m, tile_n, As, Bs, acc);
    int lane = threadIdx.x & 63, wave = threadIdx.x >> 6;
    int m_off = (wave >> 1) * 64, n_off = (wave & 1) * 64;
    int row16 = lane & 15, quad = lane >> 4;
    for (int nt = 0; nt < 4; nt++) {
        int n = tile_n + n_off + nt * 16 + row16;
        int which = n / Cc, hd = n % Cc, head = hd / Dd, dim = hd % Dd;
        size_t basep = (size_t)which * QKVW_PLANE + (size_t)head * (NC * 16 * Dd) + dim;
        for (int mt = 0; mt < 4; mt++) {
            for (int rr = 0; rr < 4; rr++) {
                int m = tile_m + m_off + mt * 16 + quad * 4 + rr;
                int b = m >> 12, pix = m & 4095;
                int y = pix >> 6, x = pix & 63;
                int win = (y >> 2) * 16 + (x >> 2);
                int pos = (y & 3) * 4 + (x & 3);
                size_t dst = basep + ((size_t)b * Hh * NC * 16 * Dd) + ((size_t)win * 16 + pos) * Dd;
                qkvw[dst] = __float2bfloat16(acc[mt][nt][rr]);
            }
        }
    }
}

// ---- 5. window attention (MFMA, one wave per window, no block barriers) ----
#define PSTRIDE 80   // shorts; 160B row stride -> 16B-aligned b128 reads
#define VSTRIDE 72   // shorts; 144B row stride -> 16B-aligned, conflict-free b128 reads
__global__ __launch_bounds__(256) void k_win_attn(const __hip_bfloat16* qkvw, const int* idx, __hip_bfloat16* yo) {
    __shared__ __align__(16) short Pl[4][16 * PSTRIDE];   // P (16q x 64k) bf16, per wave
    __shared__ __align__(16) short Vt[4][48 * VSTRIDE];   // V^T (48d x 64k) bf16, per wave
    int lane = threadIdx.x & 63, wave = threadIdx.x >> 6;
    int gw = blockIdx.x * 4 + wave;      // global window id: bh*256 + n
    int bh = gw >> 8, n = gw & 255;
    int row16 = lane & 15, quad = lane >> 4;
    const ushort* qb  = (const ushort*)qkvw + (size_t)(bh * NC + n) * 768;
    const ushort* kwb = (const ushort*)qkvw + (size_t)QKVW_PLANE + (size_t)bh * NC * 768;
    const ushort* vwb = (const ushort*)qkvw + 2 * (size_t)QKVW_PLANE + (size_t)bh * NC * 768;
    int sel[4];
    for (int g = 0; g < 4; g++) sel[g] = idx[(size_t)gw * 4 + g];
    // V gather loads (each lane owns key row = lane: window sel[lane>>4], pos lane&15)
    const ushort* vrow = vwb + (size_t)sel[quad] * 768 + row16 * 48;
    short8 vv[6];
    for (int i = 0; i < 6; i++) vv[i] = *(const short8*)(vrow + i * 8);
    // Q / K fragments straight from global (d=48: second K-step zero-padded past col 48)
    short8 zf = {0, 0, 0, 0, 0, 0, 0, 0};
    short8 aq0 = *(const short8*)(qb + row16 * 48 + quad * 8);
    short8 aq1 = (quad < 2) ? *(const short8*)(qb + row16 * 48 + 32 + quad * 8) : zf;
    floatx4 s[4];
    for (int nt = 0; nt < 4; nt++) {
        const ushort* kb = kwb + (size_t)sel[nt] * 768 + row16 * 48;
        short8 bk0 = *(const short8*)(kb + quad * 8);
        short8 bk1 = (quad < 2) ? *(const short8*)(kb + 32 + quad * 8) : zf;
        floatx4 a = {0.f, 0.f, 0.f, 0.f};
        a = __builtin_amdgcn_mfma_f32_16x16x32_bf16(aq0, bk0, a, 0, 0, 0);
        a = __builtin_amdgcn_mfma_f32_16x16x32_bf16(aq1, bk1, a, 0, 0, 0);
        s[nt] = a;   // S[q=quad*4+rr][key=nt*16+row16]
    }
    // transpose V into LDS: Vt[d][key]
    for (int i = 0; i < 6; i++)
        for (int j = 0; j < 8; j++)
            Vt[wave][(i * 8 + j) * VSTRIDE + lane] = vv[i][j];
    // softmax per row (row lives in one 16-lane quad -> shfl_xor reduction)
    for (int rr = 0; rr < 4; rr++) {
        float sv[4];
        float m = -3.402823e38f;
        for (int nt = 0; nt < 4; nt++) { sv[nt] = s[nt][rr] * SCALE; m = fmaxf(m, sv[nt]); }
        for (int msk = 1; msk < 16; msk <<= 1) m = fmaxf(m, __shfl_xor(m, msk));
        float sum = 0.f;
        for (int nt = 0; nt < 4; nt++) { sv[nt] = expf(sv[nt] - m); sum += sv[nt]; }
        for (int msk = 1; msk < 16; msk <<= 1) sum += __shfl_xor(sum, msk);
        float inv = 1.f / sum;
        for (int nt = 0; nt < 4; nt++) {
            __hip_bfloat16 hb = __float2bfloat16(sv[nt] * inv);
            Pl[wave][(quad * 4 + rr) * PSTRIDE + nt * 16 + row16] = *(short*)&hb;
        }
    }
    // PV: O[q][d], A = P (16x64), B = V^T rows (d x keys)
    floatx4 o[3];
    for (int i = 0; i < 3; i++) o[i] = (floatx4){0.f, 0.f, 0.f, 0.f};
    for (int k0 = 0; k0 < 64; k0 += 32) {
        short8 pa = *(const short8*)&Pl[wave][row16 * PSTRIDE + k0 + quad * 8];
        for (int nt2 = 0; nt2 < 3; nt2++) {
            short8 vb = *(const short8*)&Vt[wave][(nt2 * 16 + row16) * VSTRIDE + k0 + quad * 8];
            o[nt2] = __builtin_amdgcn_mfma_f32_16x16x32_bf16(pa, vb, o[nt2], 0, 0, 0);
        }
    }
    // epilogue: O[q=quad*4+rr][d=nt2*16+row16] -> yo (B,H,W,C)
    int b = bh >> 3, hh = bh & 7;
    int wy = n >> 4, wx = n & 15;
    for (int rr = 0; rr < 4; rr++) {
        int q = quad * 4 + rr;
        int y = wy * 4 + (q >> 2), x = wx * 4 + (q & 3);
        size_t base = (((size_t)(b * 64 + y)) * 64 + x) * Cc + hh * Dd;
        for (int nt2 = 0; nt2 < 3; nt2++)
            yo[base + nt2 * 16 + row16] = __float2bfloat16(o[nt2][rr]);
    }
}

// ---- 6. upsample(xo) -> dwconv(dwx) -> 0.5*xn + 0.5*yo -> zpre ----
__global__ __launch_bounds__(256) void k_up_mix(const __hip_bfloat16* xo, const __hip_bfloat16* yo,
                                                const __hip_bfloat16* dwx_w, const __hip_bfloat16* dwx_b,
                                                __hip_bfloat16* zpre) {
    __shared__ float wsm[Cc * 9];
    __shared__ float bsm[Cc];
    for (int e = threadIdx.x; e < Cc * 9; e += 256) wsm[e] = __bfloat162float(dwx_w[e]);
    for (int e = threadIdx.x; e < Cc; e += 256) bsm[e] = __bfloat162float(dwx_b[e]);
    __syncthreads();
    size_t gid = (size_t)blockIdx.x * 256 + threadIdx.x;
    int c = (int)(gid % Cc);
    size_t p = gid / Cc;
    int x = (int)(p % 64); p /= 64;
    int y = (int)(p % 64);
    int b = (int)(p / 64);
    float acc = bsm[c];
    for (int di = 0; di < 3; di++) {
        int yy = y + di - 1;
        if (yy < 0 || yy > 63) continue;
        for (int dj = 0; dj < 3; dj++) {
            int xx = x + dj - 1;
            if (xx < 0 || xx > 63) continue;
            acc += __bfloat162float(xo[((size_t)(b * NC + (yy >> 2) * 16 + (xx >> 2))) * Cc + c]) * wsm[c * 9 + di * 3 + dj];
        }
    }
    float z = 0.5f * acc + 0.5f * __bfloat162float(yo[gid]);
    zpre[gid] = __float2bfloat16(z);
}

// ---- 7. dwconv(dw) on zpre -> z ----
__global__ __launch_bounds__(256) void k_dw2(const __hip_bfloat16* zpre, const __hip_bfloat16* dw_w,
                                             const __hip_bfloat16* dw_b, __hip_bfloat16* z) {
    __shared__ float wsm[Cc * 9];
    __shared__ float bsm[Cc];
    for (int e = threadIdx.x; e < Cc * 9; e += 256) wsm[e] = __bfloat162float(dw_w[e]);
    for (int e = threadIdx.x; e < Cc; e += 256) bsm[e] = __bfloat162float(dw_b[e]);
    __syncthreads();
    size_t gid = (size_t)blockIdx.x * 256 + threadIdx.x;
    int c = (int)(gid % Cc);
    size_t p = gid / Cc;
    int x = (int)(p % 64); p /= 64;
    int y = (int)(p % 64);
    int b = (int)(p / 64);
    float acc = bsm[c];
    for (int di = 0; di < 3; di++) {
        int yy = y + di - 1;
        if (yy < 0 || yy > 63) continue;
        for (int dj = 0; dj < 3; dj++) {
            int xx = x + dj - 1;
            if (xx < 0 || xx > 63) continue;
            acc += __bfloat162float(zpre[(((size_t)(b * 64 + yy)) * 64 + xx) * Cc + c]) * wsm[c * 9 + di * 3 + dj];
        }
    }
    z[gid] = __float2bfloat16(acc);
}

// ---- 8. pointwise gemm (tiled): (32768x384)@(384x384)^T + bias -> out (dtype per flag) ----
__global__ __launch_bounds__(256) void k_gemm_pw(const ushort* Z, const ushort* W, const __hip_bfloat16* bias,
                                                 void* out, const int* flag) {
    __shared__ __align__(16) short As[128 * 32];
    __shared__ __align__(16) short Bs[128 * 32];
    floatx4 acc[4][4];
    int tile_m = blockIdx.y * 128, tile_n = blockIdx.x * 128;
    gemm128(Z, W, tile_m, tile_n, As, Bs, acc);
    int lane = threadIdx.x & 63, wave = threadIdx.x >> 6;
    int m_off = (wave >> 1) * 64, n_off = (wave & 1) * 64;
    int row16 = lane & 15, quad = lane >> 4;
    int f32out = *flag;
    for (int nt = 0; nt < 4; nt++) {
        int n = tile_n + n_off + nt * 16 + row16;
        float bv = __bfloat162float(bias[n]);
        for (int mt = 0; mt < 4; mt++) {
            for (int rr = 0; rr < 4; rr++) {
                int m = tile_m + m_off + mt * 16 + quad * 4 + rr;
                float v = acc[mt][nt][rr] + bv;
                if (f32out) ((float*)out)[(size_t)m * Cc + n] = v;
                else ((__hip_bfloat16*)out)[(size_t)m * Cc + n] = __float2bfloat16(v);
            }
        }
    }
}

extern "C" void kernel_launch(void* const* d_in, const int* in_sizes, int n_in,
                              void* d_out, int out_size, void* d_ws, size_t ws_size,
                              hipStream_t stream) {
    char* ws = (char*)d_ws;
    float*          qkvc = (float*)(ws);                        //  9,437,184 B (3 f32 planes)
    __hip_bfloat16* xc   = (__hip_bfloat16*)(ws +  9437184);    //  1,572,864 B
    int*            idx  = (int*)(ws + 11010048);               //    262,144 B
    __hip_bfloat16* xo   = (__hip_bfloat16*)(ws + 11272192);    //  1,572,864 B
    __hip_bfloat16* qkvw = (__hip_bfloat16*)(ws + 12845056);    // 75,497,472 B (3 bf16 planes)
    __hip_bfloat16* yo   = (__hip_bfloat16*)(ws + 88342528);    // 25,165,824 B
    __hip_bfloat16* xbf  = (__hip_bfloat16*)(ws + 88342528);    // aliases yo (x dead before win_attn)
    __hip_bfloat16* zpre = (__hip_bfloat16*)(ws + 12845056);    // aliases qkvw (dead after win_attn)
    __hip_bfloat16* zbuf = (__hip_bfloat16*)(ws + 88342528);    // aliases yo (dead after up_mix)
    __hip_bfloat16* wqkv = (__hip_bfloat16*)(ws + 113508352);   //   884,736 B
    __hip_bfloat16* wdwx = (__hip_bfloat16*)(ws + 114393088);
    __hip_bfloat16* bdwx = (__hip_bfloat16*)(ws + 114400000);
    __hip_bfloat16* wdw  = (__hip_bfloat16*)(ws + 114400768);
    __hip_bfloat16* bdw  = (__hip_bfloat16*)(ws + 114407680);
    __hip_bfloat16* wpw  = (__hip_bfloat16*)(ws + 114408448);
    __hip_bfloat16* bpw  = (__hip_bfloat16*)(ws + 114703360);
    int*            flag = (int*)(ws + 114704128);

    k_detect<<<1, 256, 0, stream>>>((const ushort*)d_in[0], flag);
    k_convert<<<49152, 256, 0, stream>>>(d_in[0], xbf, 12582912, flag);
    k_convert<<<1728, 256, 0, stream>>>(d_in[1], wqkv, 442368, flag);
    k_convert<<<14, 256, 0, stream>>>(d_in[2], wdwx, 3456, flag);
    k_convert<<<2, 256, 0, stream>>>(d_in[3], bdwx, 384, flag);
    k_convert<<<14, 256, 0, stream>>>(d_in[4], wdw, 3456, flag);
    k_convert<<<2, 256, 0, stream>>>(d_in[5], bdw, 384, flag);
    k_convert<<<576, 256, 0, stream>>>(d_in[6], wpw, 147456, flag);
    k_convert<<<2, 256, 0, stream>>>(d_in[7], bpw, 384, flag);

    k_pool<<<2048, 256, 0, stream>>>(xbf, xc);
    k_gemm_qkv_coarse<<<dim3(36, 64), 256, 0, stream>>>((const ushort*)xc, (const ushort*)wqkv, qkvc);
    k_coarse_attn<<<16384, 256, 0, stream>>>(qkvc, idx, xo);
    k_gemm_qkv_fine<<<dim3(9, 256), 256, 0, stream>>>((const ushort*)xbf, (const ushort*)wqkv, qkvw);
    k_win_attn<<<4096, 256, 0, stream>>>(qkvw, idx, yo);
    k_up_mix<<<49152, 256, 0, stream>>>(xo, yo, wdwx, bdwx, zpre);
    k_dw2<<<49152, 256, 0, stream>>>(zpre, wdw, bdw, zbuf);
    k_gemm_pw<<<dim3(3, 256), 256, 0, stream>>>((const ushort*)zbuf, (const ushort*)wpw, bpw, d_out, flag);
}

// Round 5
// 485.780 us; speedup vs baseline: 2.7793x; 1.3809x over previous
//
#include <hip/hip_runtime.h>
#include <hip/hip_bf16.h>

// MultiStreamAttention: B=8 H=W=64 C=384, heads=8 d=48, r=4 -> Hc=Wc=16 Nc=256, topk=4
// Inputs f32 or bf16 (runtime-detected); compute bf16 MFMA / f32 accum; output per detected mode.

#define Bq 8
#define Hh 8
#define Dd 48
#define Cc 384
#define NC 256
#define MFINE 32768    // B*H*W
#define KDIM 384
#define SCALE 0.14433756729740643f  // 1/sqrt(48)

typedef __attribute__((ext_vector_type(8))) short short8;
typedef __attribute__((ext_vector_type(4))) float floatx4;

// plane strides (elements)
#define QKVC_PLANE 786432      // B*h*Nc*d
#define QKVW_PLANE 12582912    // B*h*Nc*16*d

// ---- 0a. dtype detector: flag=1 if inputs are f32, 0 if bf16 ----
__global__ __launch_bounds__(256) void k_detect(const ushort* x, int* flag) {
    __shared__ int cnt;
    if (threadIdx.x == 0) cnt = 0;
    __syncthreads();
    int c = 0;
    for (int i = threadIdx.x; i < 8192; i += 256) {
        int e = (x[i] >> 7) & 0xFF;
        if (e >= 0xC1) c++;   // |v| >= 2^66: never for sane bf16 data, ~12% for f32-as-bf16
    }
    atomicAdd(&cnt, c);
    __syncthreads();
    if (threadIdx.x == 0) *flag = (cnt > 16) ? 1 : 0;
}

// ---- 0b. canonicalize input to bf16 ----
__global__ __launch_bounds__(256) void k_convert(const void* src, __hip_bfloat16* dst, int n, const int* flag) {
    int i = blockIdx.x * 256 + threadIdx.x;
    if (i >= n) return;
    if (*flag) dst[i] = __float2bfloat16(((const float*)src)[i]);
    else       dst[i] = ((const __hip_bfloat16*)src)[i];
}

// ---- async global->LDS, 16B per lane, wave-uniform LDS base ----
__device__ __forceinline__ void gload_lds16(const ushort* g, short* l) {
    __builtin_amdgcn_global_load_lds(
        (const __attribute__((address_space(1))) unsigned int*)(g),
        (__attribute__((address_space(3))) unsigned int*)(l), 16, 0, 0);
}

// ---- m97-style 128x128 tiled GEMM core: C[128x128] = A[128xK] * B[128xK]^T ----
__device__ __forceinline__ void gemm128(const ushort* A, const ushort* B,
                                        int tile_m, int tile_n,
                                        short* As, short* Bs, floatx4 (&acc)[4][4]) {
    int lane = threadIdx.x & 63, wave = threadIdx.x >> 6;
    int m_off = (wave >> 1) * 64, n_off = (wave & 1) * 64;
    int row16 = lane & 15, quad = lane >> 4;
    int srow = lane >> 2;
    int scol = (lane & 3) * 8;
    for (int i = 0; i < 4; i++)
        for (int j = 0; j < 4; j++)
            acc[i][j] = (floatx4){0.f, 0.f, 0.f, 0.f};
    for (int k0 = 0; k0 < KDIM; k0 += 32) {
        for (int g = wave; g < 8; g += 4) {
            int r = g * 16 + srow;
            gload_lds16(A + (size_t)(tile_m + r) * KDIM + k0 + scol, As + g * 512);
            gload_lds16(B + (size_t)(tile_n + r) * KDIM + k0 + scol, Bs + g * 512);
        }
        __syncthreads();
        short8 af[4], bf[4];
        for (int mt = 0; mt < 4; mt++)
            af[mt] = *(const short8*)(As + (m_off + mt * 16 + row16) * 32 + quad * 8);
        for (int nt = 0; nt < 4; nt++)
            bf[nt] = *(const short8*)(Bs + (n_off + nt * 16 + row16) * 32 + quad * 8);
        for (int mt = 0; mt < 4; mt++)
            for (int nt = 0; nt < 4; nt++)
                acc[mt][nt] = __builtin_amdgcn_mfma_f32_16x16x32_bf16(af[mt], bf[nt], acc[mt][nt], 0, 0, 0);
        __syncthreads();
    }
}

// naive per-wave 16x16 tile (small coarse GEMM)
__device__ __forceinline__ floatx4 mfma_tile(const ushort* A, const ushort* W,
                                             int tile_m, int tile_n, int lane) {
    int row16 = lane & 15, quad = lane >> 4;
    const ushort* arow = A + (size_t)(tile_m + row16) * KDIM + quad * 8;
    const ushort* brow = W + (size_t)(tile_n + row16) * KDIM + quad * 8;
    floatx4 acc = {0.f, 0.f, 0.f, 0.f};
    for (int kk = 0; kk < KDIM; kk += 32) {
        short8 af = *(const short8*)(arow + kk);
        short8 bf = *(const short8*)(brow + kk);
        acc = __builtin_amdgcn_mfma_f32_16x16x32_bf16(af, bf, acc, 0, 0, 0);
    }
    return acc;
}

// ---- 1. pool: xbf (B,64,64,C) -> xc bf16 (B*Nc, C) ----
__global__ __launch_bounds__(256) void k_pool(const __hip_bfloat16* x, __hip_bfloat16* xc) {
    int blk = blockIdx.x;            // b*256 + n
    int b = blk >> 8, n = blk & 255;
    int yc = n >> 4, xcc = n & 15;
    for (int c = threadIdx.x; c < Cc; c += blockDim.x) {
        float s = 0.f;
        for (int i = 0; i < 4; i++)
            for (int j = 0; j < 4; j++)
                s += __bfloat162float(x[(((size_t)(b * 64 + yc * 4 + i)) * 64 + xcc * 4 + j) * Cc + c]);
        xc[(size_t)blk * Cc + c] = __float2bfloat16(s * 0.0625f);
    }
}

// ---- 2. coarse qkv gemm: (2048x384)@(1152x384)^T -> q/k/v f32 planes (B,h,Nc,d) ----
__global__ __launch_bounds__(256) void k_gemm_qkv_coarse(const ushort* A, const ushort* W, float* qkvc) {
    int lane = threadIdx.x & 63, wave = threadIdx.x >> 6;
    int tile_m = blockIdx.y * 32 + (wave >> 1) * 16;
    int tile_n = blockIdx.x * 32 + (wave & 1) * 16;
    floatx4 acc = mfma_tile(A, W, tile_m, tile_n, lane);
    int row16 = lane & 15, quad = lane >> 4;
    int n = tile_n + row16;
    int which = n / Cc, hd = n % Cc, head = hd / Dd, dim = hd % Dd;
    for (int rr = 0; rr < 4; rr++) {
        int m = tile_m + quad * 4 + rr;
        int b = m >> 8, nc = m & 255;
        qkvc[(size_t)which * QKVC_PLANE + (((size_t)(b * Hh + head) * NC + nc) * Dd + dim)] = acc[rr];
    }
}

// ---- 3. coarse attention: per (b,h,qi) block ----
__global__ __launch_bounds__(256) void k_coarse_attn(const float* qkvc, int* idx_out, __hip_bfloat16* xo) {
    __shared__ float qs[Dd];
    __shared__ float lg[NC];
    __shared__ float rv[NC];
    __shared__ int ri[NC];
    __shared__ float ps[NC];
    __shared__ int sel[4];
    __shared__ unsigned char chosen[NC];
    int t = threadIdx.x;
    int bh = blockIdx.x >> 8;   // b*8+h
    int qi = blockIdx.x & 255;
    const float* qp = qkvc + ((size_t)bh * NC + qi) * Dd;
    const float* kp = qkvc + QKVC_PLANE + (size_t)bh * NC * Dd;
    const float* vp = qkvc + 2 * QKVC_PLANE + (size_t)bh * NC * Dd;
    if (t < Dd) qs[t] = qp[t];
    chosen[t] = 0;
    __syncthreads();
    {
        const float* kr = kp + (size_t)t * Dd;
        float s = 0.f;
        for (int j = 0; j < Dd; j++) s += qs[j] * kr[j];
        lg[t] = s * SCALE;
    }
    __syncthreads();
    for (int it = 0; it < 4; it++) {
        rv[t] = chosen[t] ? -3.402823e38f : lg[t];
        ri[t] = t;
        __syncthreads();
        for (int st = 128; st > 0; st >>= 1) {
            if (t < st) {
                float ov = rv[t + st]; int oi = ri[t + st];
                if (ov > rv[t] || (ov == rv[t] && oi < ri[t])) { rv[t] = ov; ri[t] = oi; }
            }
            __syncthreads();
        }
        if (t == 0) { sel[it] = ri[0]; chosen[ri[0]] = 1; }
        __syncthreads();
    }
    if (t < 4) idx_out[(size_t)blockIdx.x * 4 + t] = sel[t];
    rv[t] = lg[t];
    __syncthreads();
    for (int st = 128; st > 0; st >>= 1) { if (t < st) rv[t] = fmaxf(rv[t], rv[t + st]); __syncthreads(); }
    float mx = rv[0];
    __syncthreads();
    float e = expf(lg[t] - mx);
    ps[t] = e; rv[t] = e;
    __syncthreads();
    for (int st = 128; st > 0; st >>= 1) { if (t < st) rv[t] += rv[t + st]; __syncthreads(); }
    float inv = 1.0f / rv[0];
    __syncthreads();
    if (t < Dd) {
        float acc = 0.f;
        for (int k = 0; k < NC; k++) acc += ps[k] * vp[(size_t)k * Dd + t];
        acc *= inv;
        int b = bh >> 3, hh = bh & 7;
        xo[((size_t)(b * NC + qi)) * Cc + hh * Dd + t] = __float2bfloat16(acc);
    }
}

// ---- 4. fine qkv gemm (tiled): (32768x384)@(1152x384)^T -> window-layout bf16 planes ----
__global__ __launch_bounds__(256) void k_gemm_qkv_fine(const ushort* A, const ushort* W, __hip_bfloat16* qkvw) {
    __shared__ __align__(16) short As[128 * 32];
    __shared__ __align__(16) short Bs[128 * 32];
    floatx4 acc[4][4];
    int tile_m = blockIdx.y * 128, tile_n = blockIdx.x * 128;
    gemm128(A, W, tile_m, tile_n, As, Bs, acc);
    int lane = threadIdx.x & 63, wave = threadIdx.x >> 6;
    int m_off = (wave >> 1) * 64, n_off = (wave & 1) * 64;
    int row16 = lane & 15, quad = lane >> 4;
    for (int nt = 0; nt < 4; nt++) {
        int n = tile_n + n_off + nt * 16 + row16;
        int which = n / Cc, hd = n % Cc, head = hd / Dd, dim = hd % Dd;
        size_t basep = (size_t)which * QKVW_PLANE + (size_t)head * (NC * 16 * Dd) + dim;
        for (int mt = 0; mt < 4; mt++) {
            for (int rr = 0; rr < 4; rr++) {
                int m = tile_m + m_off + mt * 16 + quad * 4 + rr;
                int b = m >> 12, pix = m & 4095;
                int y = pix >> 6, x = pix & 63;
                int win = (y >> 2) * 16 + (x >> 2);
                int pos = (y & 3) * 4 + (x & 3);
                size_t dst = basep + ((size_t)b * Hh * NC * 16 * Dd) + ((size_t)win * 16 + pos) * Dd;
                qkvw[dst] = __float2bfloat16(acc[mt][nt][rr]);
            }
        }
    }
}

// ---- 5. window attention (MFMA, one wave per window, no block barriers) ----
#define PSTRIDE 80   // shorts; 160B row stride -> 16B-aligned b128 reads
#define VSTRIDE 72   // shorts; 144B row stride -> 16B-aligned, conflict-free b128 reads
__global__ __launch_bounds__(256) void k_win_attn(const __hip_bfloat16* qkvw, const int* idx, __hip_bfloat16* yo) {
    __shared__ __align__(16) short Pl[4][16 * PSTRIDE];   // P (16q x 64k) bf16, per wave
    __shared__ __align__(16) short Vt[4][48 * VSTRIDE];   // V^T (48d x 64k) bf16, per wave
    int lane = threadIdx.x & 63, wave = threadIdx.x >> 6;
    int gw = blockIdx.x * 4 + wave;      // global window id: bh*256 + n
    int bh = gw >> 8, n = gw & 255;
    int row16 = lane & 15, quad = lane >> 4;
    const ushort* qb  = (const ushort*)qkvw + (size_t)(bh * NC + n) * 768;
    const ushort* kwb = (const ushort*)qkvw + (size_t)QKVW_PLANE + (size_t)bh * NC * 768;
    const ushort* vwb = (const ushort*)qkvw + 2 * (size_t)QKVW_PLANE + (size_t)bh * NC * 768;
    int sel[4];
    for (int g = 0; g < 4; g++) sel[g] = idx[(size_t)gw * 4 + g];
    const ushort* vrow = vwb + (size_t)sel[quad] * 768 + row16 * 48;
    short8 vv[6];
    for (int i = 0; i < 6; i++) vv[i] = *(const short8*)(vrow + i * 8);
    short8 zf = {0, 0, 0, 0, 0, 0, 0, 0};
    short8 aq0 = *(const short8*)(qb + row16 * 48 + quad * 8);
    short8 aq1 = (quad < 2) ? *(const short8*)(qb + row16 * 48 + 32 + quad * 8) : zf;
    floatx4 s[4];
    for (int nt = 0; nt < 4; nt++) {
        const ushort* kb = kwb + (size_t)sel[nt] * 768 + row16 * 48;
        short8 bk0 = *(const short8*)(kb + quad * 8);
        short8 bk1 = (quad < 2) ? *(const short8*)(kb + 32 + quad * 8) : zf;
        floatx4 a = {0.f, 0.f, 0.f, 0.f};
        a = __builtin_amdgcn_mfma_f32_16x16x32_bf16(aq0, bk0, a, 0, 0, 0);
        a = __builtin_amdgcn_mfma_f32_16x16x32_bf16(aq1, bk1, a, 0, 0, 0);
        s[nt] = a;   // S[q=quad*4+rr][key=nt*16+row16]
    }
    for (int i = 0; i < 6; i++)
        for (int j = 0; j < 8; j++)
            Vt[wave][(i * 8 + j) * VSTRIDE + lane] = vv[i][j];
    for (int rr = 0; rr < 4; rr++) {
        float sv[4];
        float m = -3.402823e38f;
        for (int nt = 0; nt < 4; nt++) { sv[nt] = s[nt][rr] * SCALE; m = fmaxf(m, sv[nt]); }
        for (int msk = 1; msk < 16; msk <<= 1) m = fmaxf(m, __shfl_xor(m, msk));
        float sum = 0.f;
        for (int nt = 0; nt < 4; nt++) { sv[nt] = expf(sv[nt] - m); sum += sv[nt]; }
        for (int msk = 1; msk < 16; msk <<= 1) sum += __shfl_xor(sum, msk);
        float inv = 1.f / sum;
        for (int nt = 0; nt < 4; nt++) {
            __hip_bfloat16 hb = __float2bfloat16(sv[nt] * inv);
            Pl[wave][(quad * 4 + rr) * PSTRIDE + nt * 16 + row16] = *(short*)&hb;
        }
    }
    floatx4 o[3];
    for (int i = 0; i < 3; i++) o[i] = (floatx4){0.f, 0.f, 0.f, 0.f};
    for (int k0 = 0; k0 < 64; k0 += 32) {
        short8 pa = *(const short8*)&Pl[wave][row16 * PSTRIDE + k0 + quad * 8];
        for (int nt2 = 0; nt2 < 3; nt2++) {
            short8 vb = *(const short8*)&Vt[wave][(nt2 * 16 + row16) * VSTRIDE + k0 + quad * 8];
            o[nt2] = __builtin_amdgcn_mfma_f32_16x16x32_bf16(pa, vb, o[nt2], 0, 0, 0);
        }
    }
    int b = bh >> 3, hh = bh & 7;
    int wy = n >> 4, wx = n & 15;
    for (int rr = 0; rr < 4; rr++) {
        int q = quad * 4 + rr;
        int y = wy * 4 + (q >> 2), x = wx * 4 + (q & 3);
        size_t base = (((size_t)(b * 64 + y)) * 64 + x) * Cc + hh * Dd;
        for (int nt2 = 0; nt2 < 3; nt2++)
            yo[base + nt2 * 16 + row16] = __float2bfloat16(o[nt2][rr]);
    }
}

// ---- 6. upsample(xo)->dwconv(dwx)->0.5 mix with yo -> zpre. Row-sliding, weights in regs, no div ----
__global__ __launch_bounds__(384) void k_up_mix(const __hip_bfloat16* xo, const __hip_bfloat16* yo,
                                                const __hip_bfloat16* dwx_w, const __hip_bfloat16* dwx_b,
                                                __hip_bfloat16* zpre) {
    int c = threadIdx.x;             // channel
    int by = blockIdx.x;             // b*64 + y
    int y = by & 63, b = by >> 6;
    float w[9];
    for (int k = 0; k < 9; k++) w[k] = __bfloat162float(dwx_w[c * 9 + k]);
    float bias = __bfloat162float(dwx_b[c]);
    const __hip_bfloat16* xrow[3];   // coarse rows (yy>>2), null if yy out of range
    for (int di = 0; di < 3; di++) {
        int yy = y + di - 1;
        xrow[di] = (yy >= 0 && yy < 64) ? xo + ((size_t)(b * NC + (yy >> 2) * 16)) * Cc + c : nullptr;
    }
    float vL[3], vM[3], vR[3];       // coarse cols (x-1)>>2, x>>2, (x+1)>>2
    for (int di = 0; di < 3; di++) {
        vL[di] = 0.f;
        vM[di] = xrow[di] ? __bfloat162float(xrow[di][0]) : 0.f;
        vR[di] = vM[di];             // (0+1)>>2 == 0
    }
    size_t obase = (size_t)by * 64 * Cc + c;
    for (int x = 0; x < 64; x++) {
        float acc = bias;
        for (int di = 0; di < 3; di++)
            acc += vL[di] * w[di * 3] + vM[di] * w[di * 3 + 1] + vR[di] * w[di * 3 + 2];
        float zv = 0.5f * acc + 0.5f * __bfloat162float(yo[obase + (size_t)x * Cc]);
        zpre[obase + (size_t)x * Cc] = __float2bfloat16(zv);
        for (int di = 0; di < 3; di++) { vL[di] = vM[di]; vM[di] = vR[di]; }
        int nx = x + 2;              // coarse col for next iteration's right tap
        if ((nx & 3) == 0 || nx > 63) {
            int ncol = nx >> 2;
            for (int di = 0; di < 3; di++)
                vR[di] = (nx <= 63 && xrow[di]) ? __bfloat162float(xrow[di][(size_t)ncol * Cc]) : 0.f;
        }
    }
}

// ---- 7. dwconv(dw) on zpre -> z. Row-sliding, weights in regs, prefetched col, no div ----
__global__ __launch_bounds__(384) void k_dw2(const __hip_bfloat16* zpre, const __hip_bfloat16* dw_w,
                                             const __hip_bfloat16* dw_b, __hip_bfloat16* z) {
    int c = threadIdx.x;
    int by = blockIdx.x;             // b*64 + y
    int y = by & 63, b = by >> 6;
    float w[9];
    for (int k = 0; k < 9; k++) w[k] = __bfloat162float(dw_w[c * 9 + k]);
    float bias = __bfloat162float(dw_b[c]);
    const __hip_bfloat16* row[3];
    for (int di = 0; di < 3; di++) {
        int yy = y + di - 1;
        row[di] = (yy >= 0 && yy < 64) ? zpre + ((size_t)(b * 64 + yy) * 64) * Cc + c : nullptr;
    }
    float pv[3], cv[3], fut[3];
    for (int di = 0; di < 3; di++) {
        pv[di] = 0.f;
        cv[di] = row[di] ? __bfloat162float(row[di][0]) : 0.f;
        fut[di] = row[di] ? __bfloat162float(row[di][(size_t)Cc]) : 0.f;   // col 1
    }
    size_t obase = (size_t)by * 64 * Cc + c;
    for (int x = 0; x < 64; x++) {
        float nv[3];
        for (int di = 0; di < 3; di++) nv[di] = fut[di];
        int nx = x + 2;              // prefetch col used next iteration
        for (int di = 0; di < 3; di++)
            fut[di] = (nx < 64 && row[di]) ? __bfloat162float(row[di][(size_t)nx * Cc]) : 0.f;
        float acc = bias;
        for (int di = 0; di < 3; di++)
            acc += pv[di] * w[di * 3] + cv[di] * w[di * 3 + 1] + nv[di] * w[di * 3 + 2];
        z[obase + (size_t)x * Cc] = __float2bfloat16(acc);
        for (int di = 0; di < 3; di++) { pv[di] = cv[di]; cv[di] = nv[di]; }
    }
}

// ---- 8. pointwise gemm (tiled): (32768x384)@(384x384)^T + bias -> out (dtype per flag) ----
__global__ __launch_bounds__(256) void k_gemm_pw(const ushort* Z, const ushort* W, const __hip_bfloat16* bias,
                                                 void* out, const int* flag) {
    __shared__ __align__(16) short As[128 * 32];
    __shared__ __align__(16) short Bs[128 * 32];
    floatx4 acc[4][4];
    int tile_m = blockIdx.y * 128, tile_n = blockIdx.x * 128;
    gemm128(Z, W, tile_m, tile_n, As, Bs, acc);
    int lane = threadIdx.x & 63, wave = threadIdx.x >> 6;
    int m_off = (wave >> 1) * 64, n_off = (wave & 1) * 64;
    int row16 = lane & 15, quad = lane >> 4;
    int f32out = *flag;
    for (int nt = 0; nt < 4; nt++) {
        int n = tile_n + n_off + nt * 16 + row16;
        float bv = __bfloat162float(bias[n]);
        for (int mt = 0; mt < 4; mt++) {
            for (int rr = 0; rr < 4; rr++) {
                int m = tile_m + m_off + mt * 16 + quad * 4 + rr;
                float v = acc[mt][nt][rr] + bv;
                if (f32out) ((float*)out)[(size_t)m * Cc + n] = v;
                else ((__hip_bfloat16*)out)[(size_t)m * Cc + n] = __float2bfloat16(v);
            }
        }
    }
}

extern "C" void kernel_launch(void* const* d_in, const int* in_sizes, int n_in,
                              void* d_out, int out_size, void* d_ws, size_t ws_size,
                              hipStream_t stream) {
    char* ws = (char*)d_ws;
    float*          qkvc = (float*)(ws);                        //  9,437,184 B (3 f32 planes)
    __hip_bfloat16* xc   = (__hip_bfloat16*)(ws +  9437184);    //  1,572,864 B
    int*            idx  = (int*)(ws + 11010048);               //    262,144 B
    __hip_bfloat16* xo   = (__hip_bfloat16*)(ws + 11272192);    //  1,572,864 B
    __hip_bfloat16* qkvw = (__hip_bfloat16*)(ws + 12845056);    // 75,497,472 B (3 bf16 planes)
    __hip_bfloat16* yo   = (__hip_bfloat16*)(ws + 88342528);    // 25,165,824 B
    __hip_bfloat16* xbf  = (__hip_bfloat16*)(ws + 88342528);    // aliases yo (x dead before win_attn)
    __hip_bfloat16* zpre = (__hip_bfloat16*)(ws + 12845056);    // aliases qkvw (dead after win_attn)
    __hip_bfloat16* zbuf = (__hip_bfloat16*)(ws + 88342528);    // aliases yo (dead after up_mix)
    __hip_bfloat16* wqkv = (__hip_bfloat16*)(ws + 113508352);   //   884,736 B
    __hip_bfloat16* wdwx = (__hip_bfloat16*)(ws + 114393088);
    __hip_bfloat16* bdwx = (__hip_bfloat16*)(ws + 114400000);
    __hip_bfloat16* wdw  = (__hip_bfloat16*)(ws + 114400768);
    __hip_bfloat16* bdw  = (__hip_bfloat16*)(ws + 114407680);
    __hip_bfloat16* wpw  = (__hip_bfloat16*)(ws + 114408448);
    __hip_bfloat16* bpw  = (__hip_bfloat16*)(ws + 114703360);
    int*            flag = (int*)(ws + 114704128);

    k_detect<<<1, 256, 0, stream>>>((const ushort*)d_in[0], flag);
    k_convert<<<49152, 256, 0, stream>>>(d_in[0], xbf, 12582912, flag);
    k_convert<<<1728, 256, 0, stream>>>(d_in[1], wqkv, 442368, flag);
    k_convert<<<14, 256, 0, stream>>>(d_in[2], wdwx, 3456, flag);
    k_convert<<<2, 256, 0, stream>>>(d_in[3], bdwx, 384, flag);
    k_convert<<<14, 256, 0, stream>>>(d_in[4], wdw, 3456, flag);
    k_convert<<<2, 256, 0, stream>>>(d_in[5], bdw, 384, flag);
    k_convert<<<576, 256, 0, stream>>>(d_in[6], wpw, 147456, flag);
    k_convert<<<2, 256, 0, stream>>>(d_in[7], bpw, 384, flag);

    k_pool<<<2048, 256, 0, stream>>>(xbf, xc);
    k_gemm_qkv_coarse<<<dim3(36, 64), 256, 0, stream>>>((const ushort*)xc, (const ushort*)wqkv, qkvc);
    k_coarse_attn<<<16384, 256, 0, stream>>>(qkvc, idx, xo);
    k_gemm_qkv_fine<<<dim3(9, 256), 256, 0, stream>>>((const ushort*)xbf, (const ushort*)wqkv, qkvw);
    k_win_attn<<<4096, 256, 0, stream>>>(qkvw, idx, yo);
    k_up_mix<<<512, 384, 0, stream>>>(xo, yo, wdwx, bdwx, zpre);
    k_dw2<<<512, 384, 0, stream>>>(zpre, wdw, bdw, zbuf);
    k_gemm_pw<<<dim3(3, 256), 256, 0, stream>>>((const ushort*)zbuf, (const ushort*)wpw, bpw, d_out, flag);
}

// Round 6
// 400.331 us; speedup vs baseline: 3.3725x; 1.2134x over previous
//
#include <hip/hip_runtime.h>
#include <hip/hip_bf16.h>

// MultiStreamAttention: B=8 H=W=64 C=384, heads=8 d=48, r=4 -> Hc=Wc=16 Nc=256, topk=4
// Inputs f32 or bf16 (runtime-detected); compute bf16 MFMA / f32 accum; output per detected mode.

#define Bq 8
#define Hh 8
#define Dd 48
#define Cc 384
#define NC 256
#define MFINE 32768    // B*H*W
#define KDIM 384
#define SCALE 0.14433756729740643f  // 1/sqrt(48)

typedef __attribute__((ext_vector_type(8))) short short8;
typedef __attribute__((ext_vector_type(4))) float floatx4;

// plane strides (elements)
#define QKVW_PLANE 12582912    // B*h*Nc*16*d

// ---- 0a. dtype detector: flag=1 if inputs are f32, 0 if bf16 ----
__global__ __launch_bounds__(256) void k_detect(const ushort* x, int* flag) {
    __shared__ int cnt;
    if (threadIdx.x == 0) cnt = 0;
    __syncthreads();
    int c = 0;
    for (int i = threadIdx.x; i < 8192; i += 256) {
        int e = (x[i] >> 7) & 0xFF;
        if (e >= 0xC1) c++;   // |v| >= 2^66: never for sane bf16 data, ~12% for f32-as-bf16
    }
    atomicAdd(&cnt, c);
    __syncthreads();
    if (threadIdx.x == 0) *flag = (cnt > 16) ? 1 : 0;
}

// ---- 0b. canonicalize input to bf16 ----
__global__ __launch_bounds__(256) void k_convert(const void* src, __hip_bfloat16* dst, int n, const int* flag) {
    int i = blockIdx.x * 256 + threadIdx.x;
    if (i >= n) return;
    if (*flag) dst[i] = __float2bfloat16(((const float*)src)[i]);
    else       dst[i] = ((const __hip_bfloat16*)src)[i];
}

// ---- async global->LDS, 16B per lane, wave-uniform LDS base ----
__device__ __forceinline__ void gload_lds16(const ushort* g, short* l) {
    __builtin_amdgcn_global_load_lds(
        (const __attribute__((address_space(1))) unsigned int*)(g),
        (__attribute__((address_space(3))) unsigned int*)(l), 16, 0, 0);
}

// ---- m97-style 128x128 tiled GEMM core: C[128x128] = A[128xK] * B[128xK]^T ----
__device__ __forceinline__ void gemm128(const ushort* A, const ushort* B,
                                        int tile_m, int tile_n,
                                        short* As, short* Bs, floatx4 (&acc)[4][4]) {
    int lane = threadIdx.x & 63, wave = threadIdx.x >> 6;
    int m_off = (wave >> 1) * 64, n_off = (wave & 1) * 64;
    int row16 = lane & 15, quad = lane >> 4;
    int srow = lane >> 2;
    int scol = (lane & 3) * 8;
    for (int i = 0; i < 4; i++)
        for (int j = 0; j < 4; j++)
            acc[i][j] = (floatx4){0.f, 0.f, 0.f, 0.f};
    for (int k0 = 0; k0 < KDIM; k0 += 32) {
        for (int g = wave; g < 8; g += 4) {
            int r = g * 16 + srow;
            gload_lds16(A + (size_t)(tile_m + r) * KDIM + k0 + scol, As + g * 512);
            gload_lds16(B + (size_t)(tile_n + r) * KDIM + k0 + scol, Bs + g * 512);
        }
        __syncthreads();
        short8 af[4], bf[4];
        for (int mt = 0; mt < 4; mt++)
            af[mt] = *(const short8*)(As + (m_off + mt * 16 + row16) * 32 + quad * 8);
        for (int nt = 0; nt < 4; nt++)
            bf[nt] = *(const short8*)(Bs + (n_off + nt * 16 + row16) * 32 + quad * 8);
        for (int mt = 0; mt < 4; mt++)
            for (int nt = 0; nt < 4; nt++)
                acc[mt][nt] = __builtin_amdgcn_mfma_f32_16x16x32_bf16(af[mt], bf[nt], acc[mt][nt], 0, 0, 0);
        __syncthreads();
    }
}

// naive per-wave 16x16 tile (small coarse GEMM)
__device__ __forceinline__ floatx4 mfma_tile(const ushort* A, const ushort* W,
                                             int tile_m, int tile_n, int lane) {
    int row16 = lane & 15, quad = lane >> 4;
    const ushort* arow = A + (size_t)(tile_m + row16) * KDIM + quad * 8;
    const ushort* brow = W + (size_t)(tile_n + row16) * KDIM + quad * 8;
    floatx4 acc = {0.f, 0.f, 0.f, 0.f};
    for (int kk = 0; kk < KDIM; kk += 32) {
        short8 af = *(const short8*)(arow + kk);
        short8 bf = *(const short8*)(brow + kk);
        acc = __builtin_amdgcn_mfma_f32_16x16x32_bf16(af, bf, acc, 0, 0, 0);
    }
    return acc;
}

// ---- 1. pool: xbf (B,64,64,C) -> xc bf16 (B*Nc, C) ----
__global__ __launch_bounds__(256) void k_pool(const __hip_bfloat16* x, __hip_bfloat16* xc) {
    int blk = blockIdx.x;            // b*256 + n
    int b = blk >> 8, n = blk & 255;
    int yc = n >> 4, xcc = n & 15;
    for (int c = threadIdx.x; c < Cc; c += blockDim.x) {
        float s = 0.f;
        for (int i = 0; i < 4; i++)
            for (int j = 0; j < 4; j++)
                s += __bfloat162float(x[(((size_t)(b * 64 + yc * 4 + i)) * 64 + xcc * 4 + j) * Cc + c]);
        xc[(size_t)blk * Cc + c] = __float2bfloat16(s * 0.0625f);
    }
}

// ---- 2. coarse qkv gemm: (2048x384)@(1152x384)^T -> split-precision bf16 planes ----
// qh/ql, kh/kl: [bh][n][48] (hi + f32-residual); vt: [bh][d][n] (transposed V)
__global__ __launch_bounds__(256) void k_gemm_qkv_coarse(const ushort* A, const ushort* W,
                                                         __hip_bfloat16* qh, __hip_bfloat16* ql,
                                                         __hip_bfloat16* kh, __hip_bfloat16* kl,
                                                         __hip_bfloat16* vt) {
    int lane = threadIdx.x & 63, wave = threadIdx.x >> 6;
    int tile_m = blockIdx.y * 32 + (wave >> 1) * 16;
    int tile_n = blockIdx.x * 32 + (wave & 1) * 16;
    floatx4 acc = mfma_tile(A, W, tile_m, tile_n, lane);
    int row16 = lane & 15, quad = lane >> 4;
    int n = tile_n + row16;
    int which = n / Cc, hd = n % Cc, head = hd / Dd, dim = hd % Dd;
    for (int rr = 0; rr < 4; rr++) {
        int m = tile_m + quad * 4 + rr;
        int b = m >> 8, nc = m & 255;
        float v = acc[rr];
        __hip_bfloat16 hi = __float2bfloat16(v);
        if (which == 0) {
            size_t p = ((size_t)((b * Hh + head) * NC + nc)) * Dd + dim;
            qh[p] = hi;
            ql[p] = __float2bfloat16(v - __bfloat162float(hi));
        } else if (which == 1) {
            size_t p = ((size_t)((b * Hh + head) * NC + nc)) * Dd + dim;
            kh[p] = hi;
            kl[p] = __float2bfloat16(v - __bfloat162float(hi));
        } else {
            vt[((size_t)((b * Hh + head) * Dd + dim)) * NC + nc] = hi;
        }
    }
}

// ---- 3. coarse attention: MFMA, one wave per 16 queries, no barriers ----
#define PST 264   // shorts; row stride for P (16q x 256k), pad 8 keeps 16B align, 2-way banks
__global__ __launch_bounds__(256) void k_coarse_attn(const ushort* qh, const ushort* ql,
                                                     const ushort* kh, const ushort* kl,
                                                     const ushort* vt,
                                                     int* idx_out, __hip_bfloat16* xo) {
    __shared__ __align__(16) short Pl[4][16 * PST];
    int lane = threadIdx.x & 63, wave = threadIdx.x >> 6;
    int bh = blockIdx.x >> 2, qt = blockIdx.x & 3;
    int row16 = lane & 15, quad = lane >> 4;
    int q0 = qt * 64 + wave * 16;
    short8 zf = {0, 0, 0, 0, 0, 0, 0, 0};
    const ushort* qhr = qh + ((size_t)(bh * NC + q0 + row16)) * Dd;
    const ushort* qlr = ql + ((size_t)(bh * NC + q0 + row16)) * Dd;
    short8 aqh0 = *(const short8*)(qhr + quad * 8);
    short8 aqh1 = (quad < 2) ? *(const short8*)(qhr + 32 + quad * 8) : zf;
    short8 aql0 = *(const short8*)(qlr + quad * 8);
    short8 aql1 = (quad < 2) ? *(const short8*)(qlr + 32 + quad * 8) : zf;
    // scores: S[q=quad*4+rr][key=nt*16+row16], 3-term split for ~f32 accuracy
    floatx4 s[16];
    for (int nt = 0; nt < 16; nt++) {
        const ushort* khr = kh + ((size_t)(bh * NC + nt * 16 + row16)) * Dd;
        const ushort* klr = kl + ((size_t)(bh * NC + nt * 16 + row16)) * Dd;
        short8 bh0 = *(const short8*)(khr + quad * 8);
        short8 bh1 = (quad < 2) ? *(const short8*)(khr + 32 + quad * 8) : zf;
        short8 bl0 = *(const short8*)(klr + quad * 8);
        short8 bl1 = (quad < 2) ? *(const short8*)(klr + 32 + quad * 8) : zf;
        floatx4 a = {0.f, 0.f, 0.f, 0.f};
        a = __builtin_amdgcn_mfma_f32_16x16x32_bf16(aqh0, bh0, a, 0, 0, 0);
        a = __builtin_amdgcn_mfma_f32_16x16x32_bf16(aqh1, bh1, a, 0, 0, 0);
        a = __builtin_amdgcn_mfma_f32_16x16x32_bf16(aqh0, bl0, a, 0, 0, 0);
        a = __builtin_amdgcn_mfma_f32_16x16x32_bf16(aqh1, bl1, a, 0, 0, 0);
        a = __builtin_amdgcn_mfma_f32_16x16x32_bf16(aql0, bh0, a, 0, 0, 0);
        a = __builtin_amdgcn_mfma_f32_16x16x32_bf16(aql1, bh1, a, 0, 0, 0);
        s[nt] = a;
    }
    // per-row: top-4 (ties -> smallest index), full-256 softmax, P -> LDS
    for (int rr = 0; rr < 4; rr++) {
        float sv[16];
        for (int nt = 0; nt < 16; nt++) sv[nt] = s[nt][rr] * SCALE;
        int chosen[4] = {-1, -1, -1, -1};
        float rowmax = 0.f;
        for (int it = 0; it < 4; it++) {
            float bv = -3.402823e38f; int bi = 0x7fffffff;
            for (int nt = 0; nt < 16; nt++) {
                int ki = nt * 16 + row16;
                bool skip = (ki == chosen[0]) | (ki == chosen[1]) | (ki == chosen[2]) | (ki == chosen[3]);
                if (!skip && sv[nt] > bv) { bv = sv[nt]; bi = ki; }
            }
            for (int mk = 1; mk < 16; mk <<= 1) {
                float ov = __shfl_xor(bv, mk); int oi = __shfl_xor(bi, mk);
                if (ov > bv || (ov == bv && oi < bi)) { bv = ov; bi = oi; }
            }
            chosen[it] = bi;
            if (it == 0) rowmax = bv;
        }
        if (row16 == 0) {
            int q = q0 + quad * 4 + rr;
            for (int it = 0; it < 4; it++)
                idx_out[((size_t)bh * NC + q) * 4 + it] = chosen[it];
        }
        float ex[16], sum = 0.f;
        for (int nt = 0; nt < 16; nt++) { ex[nt] = __expf(sv[nt] - rowmax); sum += ex[nt]; }
        for (int mk = 1; mk < 16; mk <<= 1) sum += __shfl_xor(sum, mk);
        float inv = 1.f / sum;
        for (int nt = 0; nt < 16; nt++) {
            __hip_bfloat16 hb = __float2bfloat16(ex[nt] * inv);
            Pl[wave][(quad * 4 + rr) * PST + nt * 16 + row16] = *(short*)&hb;
        }
    }
    // PV: A = P (16x256) from LDS, B = vt rows (48 x 256) from global
    const ushort* vbase = vt + (size_t)bh * Dd * NC;
    floatx4 o[3];
    for (int i = 0; i < 3; i++) o[i] = (floatx4){0.f, 0.f, 0.f, 0.f};
    for (int k0 = 0; k0 < 256; k0 += 32) {
        short8 pa = *(const short8*)&Pl[wave][row16 * PST + k0 + quad * 8];
        for (int d2 = 0; d2 < 3; d2++) {
            short8 vb = *(const short8*)(vbase + (size_t)(d2 * 16 + row16) * NC + k0 + quad * 8);
            o[d2] = __builtin_amdgcn_mfma_f32_16x16x32_bf16(pa, vb, o[d2], 0, 0, 0);
        }
    }
    int b = bh >> 3, hh = bh & 7;
    for (int rr = 0; rr < 4; rr++) {
        int q = q0 + quad * 4 + rr;
        size_t base = ((size_t)(b * NC + q)) * Cc + hh * Dd;
        for (int d2 = 0; d2 < 3; d2++)
            xo[base + d2 * 16 + row16] = __float2bfloat16(o[d2][rr]);
    }
}

// ---- 4. fine qkv gemm (tiled): (32768x384)@(1152x384)^T -> window-layout bf16 planes ----
__global__ __launch_bounds__(256) void k_gemm_qkv_fine(const ushort* A, const ushort* W, __hip_bfloat16* qkvw) {
    __shared__ __align__(16) short As[128 * 32];
    __shared__ __align__(16) short Bs[128 * 32];
    floatx4 acc[4][4];
    int tile_m = blockIdx.y * 128, tile_n = blockIdx.x * 128;
    gemm128(A, W, tile_m, tile_n, As, Bs, acc);
    int lane = threadIdx.x & 63, wave = threadIdx.x >> 6;
    int m_off = (wave >> 1) * 64, n_off = (wave & 1) * 64;
    int row16 = lane & 15, quad = lane >> 4;
    for (int nt = 0; nt < 4; nt++) {
        int n = tile_n + n_off + nt * 16 + row16;
        int which = n / Cc, hd = n % Cc, head = hd / Dd, dim = hd % Dd;
        size_t basep = (size_t)which * QKVW_PLANE + (size_t)head * (NC * 16 * Dd) + dim;
        for (int mt = 0; mt < 4; mt++) {
            for (int rr = 0; rr < 4; rr++) {
                int m = tile_m + m_off + mt * 16 + quad * 4 + rr;
                int b = m >> 12, pix = m & 4095;
                int y = pix >> 6, x = pix & 63;
                int win = (y >> 2) * 16 + (x >> 2);
                int pos = (y & 3) * 4 + (x & 3);
                size_t dst = basep + ((size_t)b * Hh * NC * 16 * Dd) + ((size_t)win * 16 + pos) * Dd;
                qkvw[dst] = __float2bfloat16(acc[mt][nt][rr]);
            }
        }
    }
}

// ---- 5. window attention (MFMA, one wave per window, no block barriers) ----
#define PSTRIDE 80   // shorts; 160B row stride -> 16B-aligned b128 reads
#define VSTRIDE 72   // shorts; 144B row stride -> 16B-aligned, conflict-free b128 reads
__global__ __launch_bounds__(256) void k_win_attn(const __hip_bfloat16* qkvw, const int* idx, __hip_bfloat16* yo) {
    __shared__ __align__(16) short Pl[4][16 * PSTRIDE];   // P (16q x 64k) bf16, per wave
    __shared__ __align__(16) short Vt[4][48 * VSTRIDE];   // V^T (48d x 64k) bf16, per wave
    int lane = threadIdx.x & 63, wave = threadIdx.x >> 6;
    int gw = blockIdx.x * 4 + wave;      // global window id: bh*256 + n
    int bh = gw >> 8, n = gw & 255;
    int row16 = lane & 15, quad = lane >> 4;
    const ushort* qb  = (const ushort*)qkvw + (size_t)(bh * NC + n) * 768;
    const ushort* kwb = (const ushort*)qkvw + (size_t)QKVW_PLANE + (size_t)bh * NC * 768;
    const ushort* vwb = (const ushort*)qkvw + 2 * (size_t)QKVW_PLANE + (size_t)bh * NC * 768;
    int sel[4];
    for (int g = 0; g < 4; g++) sel[g] = idx[(size_t)gw * 4 + g];
    const ushort* vrow = vwb + (size_t)sel[quad] * 768 + row16 * 48;
    short8 vv[6];
    for (int i = 0; i < 6; i++) vv[i] = *(const short8*)(vrow + i * 8);
    short8 zf = {0, 0, 0, 0, 0, 0, 0, 0};
    short8 aq0 = *(const short8*)(qb + row16 * 48 + quad * 8);
    short8 aq1 = (quad < 2) ? *(const short8*)(qb + row16 * 48 + 32 + quad * 8) : zf;
    floatx4 s[4];
    for (int nt = 0; nt < 4; nt++) {
        const ushort* kb = kwb + (size_t)sel[nt] * 768 + row16 * 48;
        short8 bk0 = *(const short8*)(kb + quad * 8);
        short8 bk1 = (quad < 2) ? *(const short8*)(kb + 32 + quad * 8) : zf;
        floatx4 a = {0.f, 0.f, 0.f, 0.f};
        a = __builtin_amdgcn_mfma_f32_16x16x32_bf16(aq0, bk0, a, 0, 0, 0);
        a = __builtin_amdgcn_mfma_f32_16x16x32_bf16(aq1, bk1, a, 0, 0, 0);
        s[nt] = a;   // S[q=quad*4+rr][key=nt*16+row16]
    }
    for (int i = 0; i < 6; i++)
        for (int j = 0; j < 8; j++)
            Vt[wave][(i * 8 + j) * VSTRIDE + lane] = vv[i][j];
    for (int rr = 0; rr < 4; rr++) {
        float sv[4];
        float m = -3.402823e38f;
        for (int nt = 0; nt < 4; nt++) { sv[nt] = s[nt][rr] * SCALE; m = fmaxf(m, sv[nt]); }
        for (int msk = 1; msk < 16; msk <<= 1) m = fmaxf(m, __shfl_xor(m, msk));
        float sum = 0.f;
        for (int nt = 0; nt < 4; nt++) { sv[nt] = expf(sv[nt] - m); sum += sv[nt]; }
        for (int msk = 1; msk < 16; msk <<= 1) sum += __shfl_xor(sum, msk);
        float inv = 1.f / sum;
        for (int nt = 0; nt < 4; nt++) {
            __hip_bfloat16 hb = __float2bfloat16(sv[nt] * inv);
            Pl[wave][(quad * 4 + rr) * PSTRIDE + nt * 16 + row16] = *(short*)&hb;
        }
    }
    floatx4 o[3];
    for (int i = 0; i < 3; i++) o[i] = (floatx4){0.f, 0.f, 0.f, 0.f};
    for (int k0 = 0; k0 < 64; k0 += 32) {
        short8 pa = *(const short8*)&Pl[wave][row16 * PSTRIDE + k0 + quad * 8];
        for (int nt2 = 0; nt2 < 3; nt2++) {
            short8 vb = *(const short8*)&Vt[wave][(nt2 * 16 + row16) * VSTRIDE + k0 + quad * 8];
            o[nt2] = __builtin_amdgcn_mfma_f32_16x16x32_bf16(pa, vb, o[nt2], 0, 0, 0);
        }
    }
    int b = bh >> 3, hh = bh & 7;
    int wy = n >> 4, wx = n & 15;
    for (int rr = 0; rr < 4; rr++) {
        int q = quad * 4 + rr;
        int y = wy * 4 + (q >> 2), x = wx * 4 + (q & 3);
        size_t base = (((size_t)(b * 64 + y)) * 64 + x) * Cc + hh * Dd;
        for (int nt2 = 0; nt2 < 3; nt2++)
            yo[base + nt2 * 16 + row16] = __float2bfloat16(o[nt2][rr]);
    }
}

// ---- 6. upsample(xo)->dwconv(dwx)->0.5 mix with yo -> zpre. Row-sliding, weights in regs, no div ----
__global__ __launch_bounds__(384) void k_up_mix(const __hip_bfloat16* xo, const __hip_bfloat16* yo,
                                                const __hip_bfloat16* dwx_w, const __hip_bfloat16* dwx_b,
                                                __hip_bfloat16* zpre) {
    int c = threadIdx.x;             // channel
    int by = blockIdx.x;             // b*64 + y
    int y = by & 63, b = by >> 6;
    float w[9];
    for (int k = 0; k < 9; k++) w[k] = __bfloat162float(dwx_w[c * 9 + k]);
    float bias = __bfloat162float(dwx_b[c]);
    const __hip_bfloat16* xrow[3];   // coarse rows (yy>>2), null if yy out of range
    for (int di = 0; di < 3; di++) {
        int yy = y + di - 1;
        xrow[di] = (yy >= 0 && yy < 64) ? xo + ((size_t)(b * NC + (yy >> 2) * 16)) * Cc + c : nullptr;
    }
    float vL[3], vM[3], vR[3];       // coarse cols (x-1)>>2, x>>2, (x+1)>>2
    for (int di = 0; di < 3; di++) {
        vL[di] = 0.f;
        vM[di] = xrow[di] ? __bfloat162float(xrow[di][0]) : 0.f;
        vR[di] = vM[di];             // (0+1)>>2 == 0
    }
    size_t obase = (size_t)by * 64 * Cc + c;
    for (int x = 0; x < 64; x++) {
        float acc = bias;
        for (int di = 0; di < 3; di++)
            acc += vL[di] * w[di * 3] + vM[di] * w[di * 3 + 1] + vR[di] * w[di * 3 + 2];
        float zv = 0.5f * acc + 0.5f * __bfloat162float(yo[obase + (size_t)x * Cc]);
        zpre[obase + (size_t)x * Cc] = __float2bfloat16(zv);
        for (int di = 0; di < 3; di++) { vL[di] = vM[di]; vM[di] = vR[di]; }
        int nx = x + 2;              // coarse col for next iteration's right tap
        if ((nx & 3) == 0 || nx > 63) {
            int ncol = nx >> 2;
            for (int di = 0; di < 3; di++)
                vR[di] = (nx <= 63 && xrow[di]) ? __bfloat162float(xrow[di][(size_t)ncol * Cc]) : 0.f;
        }
    }
}

// ---- 7. dwconv(dw) on zpre -> z. Row-sliding, weights in regs, prefetched col, no div ----
__global__ __launch_bounds__(384) void k_dw2(const __hip_bfloat16* zpre, const __hip_bfloat16* dw_w,
                                             const __hip_bfloat16* dw_b, __hip_bfloat16* z) {
    int c = threadIdx.x;
    int by = blockIdx.x;             // b*64 + y
    int y = by & 63, b = by >> 6;
    float w[9];
    for (int k = 0; k < 9; k++) w[k] = __bfloat162float(dw_w[c * 9 + k]);
    float bias = __bfloat162float(dw_b[c]);
    const __hip_bfloat16* row[3];
    for (int di = 0; di < 3; di++) {
        int yy = y + di - 1;
        row[di] = (yy >= 0 && yy < 64) ? zpre + ((size_t)(b * 64 + yy) * 64) * Cc + c : nullptr;
    }
    float pv[3], cv[3], fut[3];
    for (int di = 0; di < 3; di++) {
        pv[di] = 0.f;
        cv[di] = row[di] ? __bfloat162float(row[di][0]) : 0.f;
        fut[di] = row[di] ? __bfloat162float(row[di][(size_t)Cc]) : 0.f;   // col 1
    }
    size_t obase = (size_t)by * 64 * Cc + c;
    for (int x = 0; x < 64; x++) {
        float nv[3];
        for (int di = 0; di < 3; di++) nv[di] = fut[di];
        int nx = x + 2;              // prefetch col used next iteration
        for (int di = 0; di < 3; di++)
            fut[di] = (nx < 64 && row[di]) ? __bfloat162float(row[di][(size_t)nx * Cc]) : 0.f;
        float acc = bias;
        for (int di = 0; di < 3; di++)
            acc += pv[di] * w[di * 3] + cv[di] * w[di * 3 + 1] + nv[di] * w[di * 3 + 2];
        z[obase + (size_t)x * Cc] = __float2bfloat16(acc);
        for (int di = 0; di < 3; di++) { pv[di] = cv[di]; cv[di] = nv[di]; }
    }
}

// ---- 8. pointwise gemm (tiled): (32768x384)@(384x384)^T + bias -> out (dtype per flag) ----
__global__ __launch_bounds__(256) void k_gemm_pw(const ushort* Z, const ushort* W, const __hip_bfloat16* bias,
                                                 void* out, const int* flag) {
    __shared__ __align__(16) short As[128 * 32];
    __shared__ __align__(16) short Bs[128 * 32];
    floatx4 acc[4][4];
    int tile_m = blockIdx.y * 128, tile_n = blockIdx.x * 128;
    gemm128(Z, W, tile_m, tile_n, As, Bs, acc);
    int lane = threadIdx.x & 63, wave = threadIdx.x >> 6;
    int m_off = (wave >> 1) * 64, n_off = (wave & 1) * 64;
    int row16 = lane & 15, quad = lane >> 4;
    int f32out = *flag;
    for (int nt = 0; nt < 4; nt++) {
        int n = tile_n + n_off + nt * 16 + row16;
        float bv = __bfloat162float(bias[n]);
        for (int mt = 0; mt < 4; mt++) {
            for (int rr = 0; rr < 4; rr++) {
                int m = tile_m + m_off + mt * 16 + quad * 4 + rr;
                float v = acc[mt][nt][rr] + bv;
                if (f32out) ((float*)out)[(size_t)m * Cc + n] = v;
                else ((__hip_bfloat16*)out)[(size_t)m * Cc + n] = __float2bfloat16(v);
            }
        }
    }
}

extern "C" void kernel_launch(void* const* d_in, const int* in_sizes, int n_in,
                              void* d_out, int out_size, void* d_ws, size_t ws_size,
                              hipStream_t stream) {
    char* ws = (char*)d_ws;
    // coarse split-precision planes (each 786432 elems * 2B = 1,572,864 B)
    __hip_bfloat16* qhp  = (__hip_bfloat16*)(ws);
    __hip_bfloat16* qlp  = (__hip_bfloat16*)(ws + 1572864);
    __hip_bfloat16* khp  = (__hip_bfloat16*)(ws + 3145728);
    __hip_bfloat16* klp  = (__hip_bfloat16*)(ws + 4718592);
    __hip_bfloat16* vtp  = (__hip_bfloat16*)(ws + 6291456);    // ends 7,864,320
    __hip_bfloat16* xc   = (__hip_bfloat16*)(ws +  9437184);   //  1,572,864 B
    int*            idx  = (int*)(ws + 11010048);              //    262,144 B
    __hip_bfloat16* xo   = (__hip_bfloat16*)(ws + 11272192);   //  1,572,864 B
    __hip_bfloat16* qkvw = (__hip_bfloat16*)(ws + 12845056);   // 75,497,472 B (3 bf16 planes)
    __hip_bfloat16* yo   = (__hip_bfloat16*)(ws + 88342528);   // 25,165,824 B
    __hip_bfloat16* xbf  = (__hip_bfloat16*)(ws + 88342528);   // aliases yo (x dead before win_attn)
    __hip_bfloat16* zpre = (__hip_bfloat16*)(ws + 12845056);   // aliases qkvw (dead after win_attn)
    __hip_bfloat16* zbuf = (__hip_bfloat16*)(ws + 88342528);   // aliases yo (dead after up_mix)
    __hip_bfloat16* wqkv = (__hip_bfloat16*)(ws + 113508352);  //   884,736 B
    __hip_bfloat16* wdwx = (__hip_bfloat16*)(ws + 114393088);
    __hip_bfloat16* bdwx = (__hip_bfloat16*)(ws + 114400000);
    __hip_bfloat16* wdw  = (__hip_bfloat16*)(ws + 114400768);
    __hip_bfloat16* bdw  = (__hip_bfloat16*)(ws + 114407680);
    __hip_bfloat16* wpw  = (__hip_bfloat16*)(ws + 114408448);
    __hip_bfloat16* bpw  = (__hip_bfloat16*)(ws + 114703360);
    int*            flag = (int*)(ws + 114704128);

    k_detect<<<1, 256, 0, stream>>>((const ushort*)d_in[0], flag);
    k_convert<<<49152, 256, 0, stream>>>(d_in[0], xbf, 12582912, flag);
    k_convert<<<1728, 256, 0, stream>>>(d_in[1], wqkv, 442368, flag);
    k_convert<<<14, 256, 0, stream>>>(d_in[2], wdwx, 3456, flag);
    k_convert<<<2, 256, 0, stream>>>(d_in[3], bdwx, 384, flag);
    k_convert<<<14, 256, 0, stream>>>(d_in[4], wdw, 3456, flag);
    k_convert<<<2, 256, 0, stream>>>(d_in[5], bdw, 384, flag);
    k_convert<<<576, 256, 0, stream>>>(d_in[6], wpw, 147456, flag);
    k_convert<<<2, 256, 0, stream>>>(d_in[7], bpw, 384, flag);

    k_pool<<<2048, 256, 0, stream>>>(xbf, xc);
    k_gemm_qkv_coarse<<<dim3(36, 64), 256, 0, stream>>>((const ushort*)xc, (const ushort*)wqkv,
                                                        qhp, qlp, khp, klp, vtp);
    k_coarse_attn<<<256, 256, 0, stream>>>((const ushort*)qhp, (const ushort*)qlp,
                                           (const ushort*)khp, (const ushort*)klp,
                                           (const ushort*)vtp, idx, xo);
    k_gemm_qkv_fine<<<dim3(9, 256), 256, 0, stream>>>((const ushort*)xbf, (const ushort*)wqkv, qkvw);
    k_win_attn<<<4096, 256, 0, stream>>>(qkvw, idx, yo);
    k_up_mix<<<512, 384, 0, stream>>>(xo, yo, wdwx, bdwx, zpre);
    k_dw2<<<512, 384, 0, stream>>>(zpre, wdw, bdw, zbuf);
    k_gemm_pw<<<dim3(3, 256), 256, 0, stream>>>((const ushort*)zbuf, (const ushort*)wpw, bpw, d_out, flag);
}